// Round 4
// baseline (1033.738 us; speedup 1.0000x reference)
//
#include <hip/hip_runtime.h>
#include <hip/hip_bf16.h>

// ---------------- constants ----------------
// C=192, H=W=T=32, WS=4, SS=2, NH=6, HD=32, N=64 tokens/window
// L = 32768 tokens/batch, B=2 -> M = 65536 rows everywhere.
#define DI __device__ __forceinline__

typedef short bf16x8 __attribute__((ext_vector_type(8)));
typedef float f32x4 __attribute__((ext_vector_type(4)));

DI short f2bf(float f) {
    __hip_bfloat16 h = __float2bfloat16(f);
    return *reinterpret_cast<short*>(&h);
}

DI void gload_lds16(const short* gsrc, short* ldst) {
    __builtin_amdgcn_global_load_lds(
        (const __attribute__((address_space(1))) void*)gsrc,
        (__attribute__((address_space(3))) void*)ldst, 16, 0, 0);
}

// region label along one axis for the shift mask: [0,28)->0, [28,30)->1, [30,32)->2
DI int reg3(int p) { return p < 28 ? 0 : (p < 30 ? 1 : 2); }

// ---------------- input transpose: x (B,C,L) -> xf (B,L,C) f32 ----------------
__global__ __launch_bounds__(256) void transpose_in(const float* __restrict__ x,
                                                    float* __restrict__ xf) {
    __shared__ float tile[32][33];
    int b = blockIdx.z;
    int c0 = blockIdx.y * 32;
    int l0 = blockIdx.x * 32;
    int tx = threadIdx.x, ty = threadIdx.y;  // 32 x 8
#pragma unroll
    for (int i = 0; i < 32; i += 8)
        tile[ty + i][tx] = x[(long)(b * 192 + c0 + ty + i) * 32768 + l0 + tx];
    __syncthreads();
#pragma unroll
    for (int i = 0; i < 32; i += 8)
        xf[(long)(b * 32768 + l0 + ty + i) * 192 + c0 + tx] = tile[tx][ty + i];
}

// ---------------- weight prep ----------------
__global__ __launch_bounds__(256) void prep_w(const float* __restrict__ qkv_w,
                                              const float* __restrict__ proj_w,
                                              const float* __restrict__ fc1_w,
                                              const float* __restrict__ fc2_w,
                                              const float* __restrict__ pw_w,
                                              short* __restrict__ wt) {
    int i = blockIdx.x * 256 + threadIdx.x;
    float v;
    if (i < 1769472) {
        int b4 = i / 442368, r = i - b4 * 442368;
        if (r < 110592) { int n = r / 192, k = r - n * 192; v = qkv_w[b4 * 110592 + k * 576 + n]; }
        else if (r < 147456) { int r2 = r - 110592; int n = r2 / 192, k = r2 - n * 192; v = proj_w[b4 * 36864 + k * 192 + n]; }
        else if (r < 294912) { int r2 = r - 147456; int n = r2 / 192, k = r2 - n * 192; v = fc1_w[b4 * 147456 + k * 768 + n]; }
        else { int r2 = r - 294912; int n = r2 / 768, k = r2 - n * 768; v = fc2_w[b4 * 147456 + k * 192 + n]; }
        wt[i] = f2bf(v);
    } else {
        int r = i - 1769472;
        wt[i] = f2bf(pw_w[r]);
    }
}

// ---------------- LayerNorm (wave per token), optionally fused roll+window-partition ----------------
template <bool PART>
__global__ __launch_bounds__(256) void ln_k(const float* __restrict__ xf,
                                            const float* __restrict__ g,
                                            const float* __restrict__ bta,
                                            short* __restrict__ out, int shift) {
    int wv = threadIdx.x >> 6, lane = threadIdx.x & 63;
    int row = blockIdx.x * 4 + wv;
    long src;
    if (PART) {
        int b = row >> 15, r = row & 32767, widx = r >> 6, n = r & 63;
        int wh = widx >> 6, ww = (widx >> 3) & 7, wt = widx & 7;
        int ih = n >> 4, iw = (n >> 2) & 3, it = n & 3;
        int h = ((wh << 2) + ih + shift) & 31;
        int w = ((ww << 2) + iw + shift) & 31;
        int t = ((wt << 2) + it + shift) & 31;
        src = ((long)(b << 15) + (h << 10) + (w << 5) + t) * 192;
    } else {
        src = (long)row * 192;
    }
    float v[3], s = 0.f, sq = 0.f;
#pragma unroll
    for (int j = 0; j < 3; j++) {
        v[j] = xf[src + lane + 64 * j];
        s += v[j];
        sq += v[j] * v[j];
    }
#pragma unroll
    for (int o = 1; o < 64; o <<= 1) {
        s += __shfl_xor(s, o, 64);
        sq += __shfl_xor(sq, o, 64);
    }
    float mu = s * (1.f / 192.f);
    float var = sq * (1.f / 192.f) - mu * mu;
    float rstd = rsqrtf(var + 1e-5f);
    long dst = (long)row * 192;
#pragma unroll
    for (int j = 0; j < 3; j++) {
        int c = lane + 64 * j;
        out[dst + c] = f2bf((v[j] - mu) * rstd * g[c] + bta[c]);
    }
}

// ---------------- generic bf16 MFMA GEMM: out(M,N) = A(M,K) @ Bt(N,K)^T + bias ----------------
// MODE 0: out bf16   MODE 3: window-reverse+roll -> resid += v (proj)
// MODE 4: pointwise conv epilogue: BN + ReLU, write f32 channel-major output
template <int MODE>
__global__ __launch_bounds__(256) void gemm_k(
    const short* __restrict__ A, const short* __restrict__ Bt,
    const float* __restrict__ bias,
    short* __restrict__ outB, float* __restrict__ resid, float* __restrict__ outF,
    const float* __restrict__ bng, const float* __restrict__ bnb,
    int M, int N, int K, int shift) {
    __shared__ short As[128 * 64];
    __shared__ short Bs[64 * 64];
    const int tid = threadIdx.x;
    // bijective XCD-chunked swizzle (gridDim.x % 8 == 0 for all our launches)
    const int nwg = gridDim.x;
    const int wg = ((blockIdx.x & 7) * (nwg >> 3)) + (blockIdx.x >> 3);
    const int tiles_n = N >> 6;
    const int m0 = (wg / tiles_n) << 7;
    const int n0 = (wg % tiles_n) << 6;
    const int wv = tid >> 6, lane = tid & 63;
    const int lr = lane & 15, lg = lane >> 4;
    const int srow = lane >> 3;
    const int scb = ((lane & 7) ^ (lane >> 3)) << 3;

    f32x4 acc[2][4] = {};
    for (int kt = 0; kt < K; kt += 64) {
        __syncthreads();
#pragma unroll
        for (int i = 0; i < 4; i++) {
            int rbase = i * 32 + wv * 8;
            gload_lds16(A + (long)(m0 + rbase + srow) * K + kt + scb, As + rbase * 64);
        }
#pragma unroll
        for (int i = 0; i < 2; i++) {
            int rbase = i * 32 + wv * 8;
            gload_lds16(Bt + (long)(n0 + rbase + srow) * K + kt + scb, Bs + rbase * 64);
        }
        __syncthreads();
#pragma unroll
        for (int ks = 0; ks < 2; ks++) {
            bf16x8 af[2], bfv[4];
            int kb = (ks << 2) + lg;
#pragma unroll
            for (int mi = 0; mi < 2; mi++) {
                int r = (wv << 5) + (mi << 4) + lr;
                af[mi] = *(const bf16x8*)(As + r * 64 + ((kb ^ (r & 7)) << 3));
            }
#pragma unroll
            for (int ni = 0; ni < 4; ni++) {
                int r = (ni << 4) + lr;
                bfv[ni] = *(const bf16x8*)(Bs + r * 64 + ((kb ^ (r & 7)) << 3));
            }
#pragma unroll
            for (int mi = 0; mi < 2; mi++)
#pragma unroll
                for (int ni = 0; ni < 4; ni++)
                    acc[mi][ni] = __builtin_amdgcn_mfma_f32_16x16x32_bf16(
                        af[mi], bfv[ni], acc[mi][ni], 0, 0, 0);
        }
    }

#pragma unroll
    for (int mi = 0; mi < 2; mi++) {
        int rbase = m0 + (wv << 5) + (mi << 4) + (lg << 2);
#pragma unroll
        for (int ni = 0; ni < 4; ni++) {
            int col = n0 + (ni << 4) + lr;
            float bv = bias[col];
            if (MODE == 4) {
                float sc = 0.9999950000374997f * bng[col];
                float bb = bnb[col];
                f32x4 o;
#pragma unroll
                for (int e = 0; e < 4; e++) {
                    float v = (acc[mi][ni][e] + bv) * sc + bb;
                    o[e] = v > 0.f ? v : 0.f;
                }
                int b = rbase >> 15, l = rbase & 32767;
                *(f32x4*)(outF + ((long)(b * 192 + col) << 15) + l) = o;
            } else {
#pragma unroll
                for (int e = 0; e < 4; e++) {
                    int r = rbase + e;
                    float v = acc[mi][ni][e] + bv;
                    if (MODE == 0) {
                        outB[(long)r * N + col] = f2bf(v);
                    } else {  // MODE 3
                        int b = r >> 15, rr = r & 32767, widx = rr >> 6, n = rr & 63;
                        int wh = widx >> 6, ww = (widx >> 3) & 7, wt = widx & 7;
                        int ih = n >> 4, iw = (n >> 2) & 3, it = n & 3;
                        int h = ((wh << 2) + ih + shift) & 31;
                        int w = ((ww << 2) + iw + shift) & 31;
                        int t = ((wt << 2) + it + shift) & 31;
                        long tok = (long)(b << 15) + (h << 10) + (w << 5) + t;
                        resid[tok * 192 + col] += v;
                    }
                }
            }
        }
    }
}

// ---------------- fused MLP: out(XF) += gelu(A @ W1 + b1) @ W2 + b2 ----------------
// A: 65536x192 bf16 (LN2 output). Block = 128 rows x full N=192. 12 hidden chunks of 64.
// LDS: A 128x192 (49KB, XOR swz) | W1 64x192 (24.5KB) | W2 192x64 (24.5KB) | h 128x64 (16KB)
__global__ __launch_bounds__(256) void mlp_k(const short* __restrict__ A,
                                             const short* __restrict__ W1g,  // fc1T (768,192)
                                             const short* __restrict__ W2g,  // fc2T (192,768)
                                             const float* __restrict__ b1,
                                             const float* __restrict__ b2,
                                             float* __restrict__ resid) {
    __shared__ short lds[57344];
    short* As = lds;            // 24576 elems
    short* W1s = lds + 24576;   // 12288
    short* W2s = lds + 36864;   // 12288
    short* Hs = lds + 49152;    // 8192
    const int tid = threadIdx.x;
    const int wv = tid >> 6, lane = tid & 63;
    const int lr = lane & 15, lg = lane >> 4;
    const int mt = ((blockIdx.x & 7) << 6) + (blockIdx.x >> 3);  // XCD swizzle, 512 blocks
    const int m0 = mt << 7;

    // ---- prologue: stage A (swizzled via pre-swizzled source, linear LDS dest) ----
#pragma unroll
    for (int i = 0; i < 12; i++) {
        int base = i * 2048 + wv * 512;  // wave's dest elem offset
        int E = base + lane * 8;
        int row = E / 192;
        int cb = (E - row * 192) >> 3;
        gload_lds16(A + (long)(m0 + row) * 192 + ((cb ^ (row & 7)) << 3), As + base);
    }
    // stage W chunk 0
    bf16x8 w1r[6], w2r[6];
#pragma unroll
    for (int q = 0; q < 6; q++) {
        int f = q * 256 + tid;
        int r = f / 24, cb = f - r * 24;
        w1r[q] = *(const bf16x8*)(W1g + (long)r * 192 + cb * 8);
    }
#pragma unroll
    for (int q = 0; q < 6; q++) {
        int f = q * 256 + tid;
        int r = f >> 3, cb = f & 7;
        w2r[q] = *(const bf16x8*)(W2g + (long)r * 768 + cb * 8);
    }
#pragma unroll
    for (int q = 0; q < 6; q++) {
        int f = q * 256 + tid;
        int r = f / 24, cb = f - r * 24;
        *(bf16x8*)(W1s + r * 192 + ((cb ^ (r & 7)) << 3)) = w1r[q];
    }
#pragma unroll
    for (int q = 0; q < 6; q++) {
        int f = q * 256 + tid;
        int r = f >> 3, cb = f & 7;
        *(bf16x8*)(W2s + r * 64 + ((cb ^ (r & 7)) << 3)) = w2r[q];
    }
    __syncthreads();  // drains vmcnt (A gloads) + lgkm

    f32x4 acc[2][12] = {};

    for (int j = 0; j < 12; j++) {
        int jn = j < 11 ? j + 1 : 11;
        // issue W1(j+1) loads (hidden under GEMM1)
#pragma unroll
        for (int q = 0; q < 6; q++) {
            int f = q * 256 + tid;
            int r = f / 24, cb = f - r * 24;
            w1r[q] = *(const bf16x8*)(W1g + (long)(jn * 64 + r) * 192 + cb * 8);
        }
        // ---- GEMM1: h = A @ W1(j)  (128x192 @ 192x64) ----
        f32x4 hacc[2][4] = {};
#pragma unroll
        for (int kk = 0; kk < 6; kk++) {
            int kb = (kk << 2) + lg;
            bf16x8 af[2], bf[4];
#pragma unroll
            for (int mi = 0; mi < 2; mi++) {
                int r = (wv << 5) + (mi << 4) + lr;
                af[mi] = *(const bf16x8*)(As + r * 192 + ((kb ^ (lr & 7)) << 3));
            }
#pragma unroll
            for (int ni = 0; ni < 4; ni++) {
                int r = (ni << 4) + lr;
                bf[ni] = *(const bf16x8*)(W1s + r * 192 + ((kb ^ (lr & 7)) << 3));
            }
#pragma unroll
            for (int mi = 0; mi < 2; mi++)
#pragma unroll
                for (int ni = 0; ni < 4; ni++)
                    hacc[mi][ni] = __builtin_amdgcn_mfma_f32_16x16x32_bf16(
                        af[mi], bf[ni], hacc[mi][ni], 0, 0, 0);
        }
        // issue W2(j+1) loads (hidden under GELU/barrier)
#pragma unroll
        for (int q = 0; q < 6; q++) {
            int f = q * 256 + tid;
            int r = f >> 3, cb = f & 7;
            w2r[q] = *(const bf16x8*)(W2g + (long)r * 768 + jn * 64 + cb * 8);
        }
        // GELU (+bias1) into packed shorts
        short hv[2][4][4];
#pragma unroll
        for (int ni = 0; ni < 4; ni++) {
            float bv = b1[j * 64 + (ni << 4) + lr];
#pragma unroll
            for (int mi = 0; mi < 2; mi++)
#pragma unroll
                for (int e = 0; e < 4; e++) {
                    float v = hacc[mi][ni][e] + bv;
                    hv[mi][ni][e] = f2bf(0.5f * v * (1.f + erff(v * 0.70710678118654752f)));
                }
        }
        __syncthreads();  // all waves done reading W1(j) & h(j-1)
        // write W1(j+1) + h(j)
#pragma unroll
        for (int q = 0; q < 6; q++) {
            int f = q * 256 + tid;
            int r = f / 24, cb = f - r * 24;
            *(bf16x8*)(W1s + r * 192 + ((cb ^ (r & 7)) << 3)) = w1r[q];
        }
#pragma unroll
        for (int mi = 0; mi < 2; mi++)
#pragma unroll
            for (int ni = 0; ni < 4; ni++)
#pragma unroll
                for (int e = 0; e < 4; e++) {
                    int row = (wv << 5) + (mi << 4) + (lg << 2) + e;
                    int blk = (ni << 1) + (lr >> 3);
                    Hs[row * 64 + ((blk ^ (row & 7)) << 3) + (lr & 7)] = hv[mi][ni][e];
                }
        __syncthreads();  // h(j) + W1(j+1) ready; W2(j) still intact
        // ---- GEMM2: acc += h(j) @ W2(j)  (128x64 @ 64x192) ----
#pragma unroll
        for (int kk = 0; kk < 2; kk++) {
            int kb = (kk << 2) + lg;
            bf16x8 ah[2], bw[12];
#pragma unroll
            for (int mi = 0; mi < 2; mi++) {
                int r = (wv << 5) + (mi << 4) + lr;
                ah[mi] = *(const bf16x8*)(Hs + r * 64 + ((kb ^ (lr & 7)) << 3));
            }
#pragma unroll
            for (int ni = 0; ni < 12; ni++) {
                int r = (ni << 4) + lr;
                bw[ni] = *(const bf16x8*)(W2s + r * 64 + ((kb ^ (lr & 7)) << 3));
            }
#pragma unroll
            for (int mi = 0; mi < 2; mi++)
#pragma unroll
                for (int ni = 0; ni < 12; ni++)
                    acc[mi][ni] = __builtin_amdgcn_mfma_f32_16x16x32_bf16(
                        ah[mi], bw[ni], acc[mi][ni], 0, 0, 0);
        }
        __syncthreads();  // all waves done reading W2(j)
#pragma unroll
        for (int q = 0; q < 6; q++) {
            int f = q * 256 + tid;
            int r = f >> 3, cb = f & 7;
            *(bf16x8*)(W2s + r * 64 + ((cb ^ (r & 7)) << 3)) = w2r[q];
        }
        __syncthreads();  // W2(j+1) ready
    }

    // ---- epilogue: resid += acc + b2 ----
#pragma unroll
    for (int mi = 0; mi < 2; mi++) {
        int rbase = m0 + (wv << 5) + (mi << 4) + (lg << 2);
#pragma unroll
        for (int ni = 0; ni < 12; ni++) {
            int col = (ni << 4) + lr;
            float bv = b2[col];
#pragma unroll
            for (int e = 0; e < 4; e++) {
                long r = rbase + e;
                resid[r * 192 + col] += acc[mi][ni][e] + bv;
            }
        }
    }
}

// ---------------- windowed attention: one wave per (window, head) ----------------
__global__ __launch_bounds__(256) void attn_k(const short* __restrict__ qkv,
                                              const float* __restrict__ rpb,  // (343,6)
                                              short* __restrict__ o, int shifted) {
    __shared__ short lds[4 * 6144];
    const int wv = threadIdx.x >> 6, lane = threadIdx.x & 63;
    short* vT = lds + wv * 6144;
    short* P = lds + wv * 6144 + 2048;
    const int task = blockIdx.x * 4 + wv;
    const int win = task / 6, head = task - win * 6;
    const int lr = lane & 15, lg = lane >> 4;
    const long qbase = (long)win * 64 * 576 + head * 32;

    bf16x8 aq[4], bk[4];
#pragma unroll
    for (int bi = 0; bi < 4; bi++)
        aq[bi] = *(const bf16x8*)(qkv + qbase + (long)((bi << 4) + lr) * 576 + (lg << 3));
#pragma unroll
    for (int bj = 0; bj < 4; bj++)
        bk[bj] = *(const bf16x8*)(qkv + qbase + 192 + (long)((bj << 4) + lr) * 576 + (lg << 3));
    f32x4 s[4][4] = {};
#pragma unroll
    for (int bi = 0; bi < 4; bi++)
#pragma unroll
        for (int bj = 0; bj < 4; bj++)
            s[bi][bj] = __builtin_amdgcn_mfma_f32_16x16x32_bf16(aq[bi], bk[bj], s[bi][bj], 0, 0, 0);

#pragma unroll
    for (int j = 0; j < 4; j++) {
        bf16x8 vv = *(const bf16x8*)(qkv + qbase + 384 + (long)lane * 576 + (j << 3));
#pragma unroll
        for (int e = 0; e < 8; e++) {
            int d = (j << 3) + e;
            vT[d * 64 + (((lane >> 3) ^ (d & 7)) << 3) + (lane & 7)] = vv[e];
        }
    }

    const float SCALE = 0.17677669529663687f;
    int widx = win & 511;
    int wh = widx >> 6, ww = (widx >> 3) & 7, wt = widx & 7;
    int ihm[4], iwm[4], itm[4], lblm[4];
#pragma unroll
    for (int bj = 0; bj < 4; bj++) {
        int m = (bj << 4) + lr;
        ihm[bj] = m >> 4; iwm[bj] = (m >> 2) & 3; itm[bj] = m & 3;
        lblm[bj] = reg3((wh << 2) + ihm[bj]) * 9 + reg3((ww << 2) + iwm[bj]) * 3 + reg3((wt << 2) + itm[bj]);
    }
#pragma unroll
    for (int bi = 0; bi < 4; bi++) {
#pragma unroll
        for (int e = 0; e < 4; e++) {
            int n = (bi << 4) + (lg << 2) + e;
            int ihn = n >> 4, iwn = (n >> 2) & 3, itn = n & 3;
            int lbln = reg3((wh << 2) + ihn) * 9 + reg3((ww << 2) + iwn) * 3 + reg3((wt << 2) + itn);
#pragma unroll
            for (int bj = 0; bj < 4; bj++) {
                int idx = (ihn - ihm[bj] + 3) * 49 + (iwn - iwm[bj] + 3) * 7 + (itn - itm[bj] + 3);
                float bias = rpb[idx * 6 + head];
                float val = s[bi][bj][e] * SCALE + bias;
                if (shifted && lbln != lblm[bj]) val -= 100.f;
                s[bi][bj][e] = val;
            }
        }
    }

#pragma unroll
    for (int bi = 0; bi < 4; bi++) {
#pragma unroll
        for (int e = 0; e < 4; e++) {
            float mx = s[bi][0][e];
#pragma unroll
            for (int bj = 1; bj < 4; bj++) mx = fmaxf(mx, s[bi][bj][e]);
#pragma unroll
            for (int off = 1; off < 16; off <<= 1) mx = fmaxf(mx, __shfl_xor(mx, off, 64));
            float sm = 0.f;
#pragma unroll
            for (int bj = 0; bj < 4; bj++) {
                float p = __expf(s[bi][bj][e] - mx);
                s[bi][bj][e] = p;
                sm += p;
            }
#pragma unroll
            for (int off = 1; off < 16; off <<= 1) sm += __shfl_xor(sm, off, 64);
            float rinv = 1.f / sm;
            int n = (bi << 4) + (lg << 2) + e;
#pragma unroll
            for (int bj = 0; bj < 4; bj++) {
                int m = (bj << 4) + lr;
                P[n * 64 + (((m >> 3) ^ (n & 7)) << 3) + (m & 7)] = f2bf(s[bi][bj][e] * rinv);
            }
        }
    }

    f32x4 oacc[4][2] = {};
#pragma unroll
    for (int ks = 0; ks < 2; ks++) {
        bf16x8 ap[4], bv2[2];
        int kb = (ks << 2) + lg;
#pragma unroll
        for (int bi = 0; bi < 4; bi++) {
            int r = (bi << 4) + lr;
            ap[bi] = *(const bf16x8*)(P + r * 64 + ((kb ^ (r & 7)) << 3));
        }
#pragma unroll
        for (int nf = 0; nf < 2; nf++) {
            int d = (nf << 4) + lr;
            bv2[nf] = *(const bf16x8*)(vT + d * 64 + ((kb ^ (d & 7)) << 3));
        }
#pragma unroll
        for (int bi = 0; bi < 4; bi++)
#pragma unroll
            for (int nf = 0; nf < 2; nf++)
                oacc[bi][nf] = __builtin_amdgcn_mfma_f32_16x16x32_bf16(ap[bi], bv2[nf], oacc[bi][nf], 0, 0, 0);
    }
#pragma unroll
    for (int bi = 0; bi < 4; bi++)
#pragma unroll
        for (int nf = 0; nf < 2; nf++)
#pragma unroll
            for (int e = 0; e < 4; e++) {
                int n = (bi << 4) + (lg << 2) + e;
                int d = (nf << 4) + lr;
                o[((long)win * 64 + n) * 192 + head * 32 + d] = f2bf(oacc[bi][nf][e]);
            }
}

// ---------------- depthwise 3x3x3 conv, register-blocked along t ----------------
__global__ __launch_bounds__(192) void dw_k(const float* __restrict__ xf,
                                            const float* __restrict__ w,
                                            const float* __restrict__ db,
                                            short* __restrict__ out) {
    int c = threadIdx.x;
    int blk = blockIdx.x;
    int t0 = (blk & 3) << 3;
    int bhw = blk >> 2;
    int b = bhw >> 10, h = (bhw >> 5) & 31, wq = bhw & 31;

    float wr[27];
#pragma unroll
    for (int k = 0; k < 27; k++) wr[k] = w[c * 27 + k];
    float bias = db[c];
    float acc[8];
#pragma unroll
    for (int j = 0; j < 8; j++) acc[j] = bias;

#pragma unroll
    for (int a = 0; a < 3; a++) {
        int hh = h + a - 1;
        if (hh < 0 || hh > 31) continue;
#pragma unroll
        for (int bb = 0; bb < 3; bb++) {
            int ww = wq + bb - 1;
            if (ww < 0 || ww > 31) continue;
            const float* base = xf + ((long)(b << 15) + (hh << 10) + (ww << 5)) * 192 + c;
            float val[10];
#pragma unroll
            for (int tt = 0; tt < 10; tt++) {
                int t = t0 + tt - 1;
                val[tt] = (t >= 0 && t < 32) ? base[t * 192] : 0.f;
            }
#pragma unroll
            for (int d = 0; d < 3; d++) {
                float wv = wr[a * 9 + bb * 3 + d];
#pragma unroll
                for (int j = 0; j < 8; j++)
                    acc[j] = fmaf(val[j + d], wv, acc[j]);
            }
        }
    }
    long obase = ((long)(b << 15) + (h << 10) + (wq << 5) + t0) * 192 + c;
#pragma unroll
    for (int j = 0; j < 8; j++) out[obase + j * 192] = f2bf(acc[j]);
}

// ---------------- launch ----------------
extern "C" void kernel_launch(void* const* d_in, const int* in_sizes, int n_in,
                              void* d_out, int out_size, void* d_ws, size_t ws_size,
                              hipStream_t stream) {
    const float* x      = (const float*)d_in[0];
    const float* n1g    = (const float*)d_in[1];
    const float* n1b    = (const float*)d_in[2];
    const float* qkv_w  = (const float*)d_in[3];
    const float* qkv_b  = (const float*)d_in[4];
    const float* rpb    = (const float*)d_in[5];
    const float* proj_w = (const float*)d_in[6];
    const float* proj_b = (const float*)d_in[7];
    const float* n2g    = (const float*)d_in[8];
    const float* n2b    = (const float*)d_in[9];
    const float* fc1_w  = (const float*)d_in[10];
    const float* fc1_b  = (const float*)d_in[11];
    const float* fc2_w  = (const float*)d_in[12];
    const float* fc2_b  = (const float*)d_in[13];
    const float* dw_w   = (const float*)d_in[14];
    const float* dw_b   = (const float*)d_in[15];
    const float* pw_w   = (const float*)d_in[16];
    const float* pw_b   = (const float*)d_in[17];
    const float* bn_g   = (const float*)d_in[18];
    const float* bn_b   = (const float*)d_in[19];
    float* outF = (float*)d_out;

    char* ws = (char*)d_ws;
    float* XF = (float*)ws;
    short* Abuf = (short*)(ws + 50331648);
    short* Bbuf = (short*)(ws + 150994944);
    short* WT = (short*)(ws + 226492416);

    transpose_in<<<dim3(1024, 6, 2), dim3(32, 8), 0, stream>>>(x, XF);
    prep_w<<<7056, 256, 0, stream>>>(qkv_w, proj_w, fc1_w, fc2_w, pw_w, WT);

    for (int i = 0; i < 4; i++) {
        int shifted = i & 1;
        int shift = shifted ? 2 : 0;
        ln_k<true><<<16384, 256, 0, stream>>>(XF, n1g + i * 192, n1b + i * 192, Abuf, shift);
        gemm_k<0><<<4608, 256, 0, stream>>>(Abuf, WT + (long)i * 442368, qkv_b + i * 576,
                                            Bbuf, nullptr, nullptr, nullptr, nullptr,
                                            65536, 576, 192, 0);
        attn_k<<<1536, 256, 0, stream>>>(Bbuf, rpb + i * 2058, Abuf, shifted);
        gemm_k<3><<<1536, 256, 0, stream>>>(Abuf, WT + (long)i * 442368 + 110592, proj_b + i * 192,
                                            nullptr, XF, nullptr, nullptr, nullptr,
                                            65536, 192, 192, shift);
        ln_k<false><<<16384, 256, 0, stream>>>(XF, n2g + i * 192, n2b + i * 192, Bbuf, 0);
        mlp_k<<<512, 256, 0, stream>>>(Bbuf, WT + (long)i * 442368 + 147456,
                                       WT + (long)i * 442368 + 294912,
                                       fc1_b + i * 768, fc2_b + i * 192, XF);
    }

    dw_k<<<8192, 192, 0, stream>>>(XF, dw_w, dw_b, Abuf);
    gemm_k<4><<<1536, 256, 0, stream>>>(Abuf, WT + 1769472, pw_b,
                                        nullptr, nullptr, outF, bn_g, bn_b,
                                        65536, 192, 192, 0);
}

// Round 5
// 1014.146 us; speedup vs baseline: 1.0193x; 1.0193x over previous
//
#include <hip/hip_runtime.h>
#include <hip/hip_bf16.h>

// ---------------- constants ----------------
// C=192, H=W=T=32, WS=4, SS=2, NH=6, HD=32, N=64 tokens/window
// L = 32768 tokens/batch, B=2 -> M = 65536 rows everywhere.
#define DI __device__ __forceinline__

typedef short bf16x8 __attribute__((ext_vector_type(8)));
typedef float f32x4 __attribute__((ext_vector_type(4)));

DI short f2bf(float f) {
    __hip_bfloat16 h = __float2bfloat16(f);
    return *reinterpret_cast<short*>(&h);
}

DI void gload_lds16(const short* gsrc, short* ldst) {
    __builtin_amdgcn_global_load_lds(
        (const __attribute__((address_space(1))) void*)gsrc,
        (__attribute__((address_space(3))) void*)ldst, 16, 0, 0);
}

// region label along one axis for the shift mask: [0,28)->0, [28,30)->1, [30,32)->2
DI int reg3(int p) { return p < 28 ? 0 : (p < 30 ? 1 : 2); }

// ---------------- input transpose: x (B,C,L) -> xf (B,L,C) f32 ----------------
__global__ __launch_bounds__(256) void transpose_in(const float* __restrict__ x,
                                                    float* __restrict__ xf) {
    __shared__ float tile[32][33];
    int b = blockIdx.z;
    int c0 = blockIdx.y * 32;
    int l0 = blockIdx.x * 32;
    int tx = threadIdx.x, ty = threadIdx.y;  // 32 x 8
#pragma unroll
    for (int i = 0; i < 32; i += 8)
        tile[ty + i][tx] = x[(long)(b * 192 + c0 + ty + i) * 32768 + l0 + tx];
    __syncthreads();
#pragma unroll
    for (int i = 0; i < 32; i += 8)
        xf[(long)(b * 32768 + l0 + ty + i) * 192 + c0 + tx] = tile[tx][ty + i];
}

// ---------------- weight prep ----------------
__global__ __launch_bounds__(256) void prep_w(const float* __restrict__ qkv_w,
                                              const float* __restrict__ proj_w,
                                              const float* __restrict__ fc1_w,
                                              const float* __restrict__ fc2_w,
                                              const float* __restrict__ pw_w,
                                              short* __restrict__ wt) {
    int i = blockIdx.x * 256 + threadIdx.x;
    float v;
    if (i < 1769472) {
        int b4 = i / 442368, r = i - b4 * 442368;
        if (r < 110592) { int n = r / 192, k = r - n * 192; v = qkv_w[b4 * 110592 + k * 576 + n]; }
        else if (r < 147456) { int r2 = r - 110592; int n = r2 / 192, k = r2 - n * 192; v = proj_w[b4 * 36864 + k * 192 + n]; }
        else if (r < 294912) { int r2 = r - 147456; int n = r2 / 192, k = r2 - n * 192; v = fc1_w[b4 * 147456 + k * 768 + n]; }
        else { int r2 = r - 294912; int n = r2 / 768, k = r2 - n * 768; v = fc2_w[b4 * 147456 + k * 192 + n]; }
        wt[i] = f2bf(v);
    } else {
        int r = i - 1769472;
        wt[i] = f2bf(pw_w[r]);
    }
}

// ---------------- LayerNorm (wave per token), optionally fused roll+window-partition ----------------
template <bool PART>
__global__ __launch_bounds__(256) void ln_k(const float* __restrict__ xf,
                                            const float* __restrict__ g,
                                            const float* __restrict__ bta,
                                            short* __restrict__ out, int shift) {
    int wv = threadIdx.x >> 6, lane = threadIdx.x & 63;
    int row = blockIdx.x * 4 + wv;
    long src;
    if (PART) {
        int b = row >> 15, r = row & 32767, widx = r >> 6, n = r & 63;
        int wh = widx >> 6, ww = (widx >> 3) & 7, wt = widx & 7;
        int ih = n >> 4, iw = (n >> 2) & 3, it = n & 3;
        int h = ((wh << 2) + ih + shift) & 31;
        int w = ((ww << 2) + iw + shift) & 31;
        int t = ((wt << 2) + it + shift) & 31;
        src = ((long)(b << 15) + (h << 10) + (w << 5) + t) * 192;
    } else {
        src = (long)row * 192;
    }
    float v[3], s = 0.f, sq = 0.f;
#pragma unroll
    for (int j = 0; j < 3; j++) {
        v[j] = xf[src + lane + 64 * j];
        s += v[j];
        sq += v[j] * v[j];
    }
#pragma unroll
    for (int o = 1; o < 64; o <<= 1) {
        s += __shfl_xor(s, o, 64);
        sq += __shfl_xor(sq, o, 64);
    }
    float mu = s * (1.f / 192.f);
    float var = sq * (1.f / 192.f) - mu * mu;
    float rstd = rsqrtf(var + 1e-5f);
    long dst = (long)row * 192;
#pragma unroll
    for (int j = 0; j < 3; j++) {
        int c = lane + 64 * j;
        out[dst + c] = f2bf((v[j] - mu) * rstd * g[c] + bta[c]);
    }
}

// ---------------- generic bf16 MFMA GEMM: out(M,N) = A(M,K) @ Bt(N,K)^T + bias ----------------
// MODE 0: out bf16   MODE 3: window-reverse+roll -> resid += v (proj)
// MODE 4: pointwise conv epilogue: BN + ReLU, write f32 channel-major output
template <int MODE>
__global__ __launch_bounds__(256) void gemm_k(
    const short* __restrict__ A, const short* __restrict__ Bt,
    const float* __restrict__ bias,
    short* __restrict__ outB, float* __restrict__ resid, float* __restrict__ outF,
    const float* __restrict__ bng, const float* __restrict__ bnb,
    int M, int N, int K, int shift) {
    __shared__ short As[128 * 64];
    __shared__ short Bs[64 * 64];
    const int tid = threadIdx.x;
    // bijective XCD-chunked swizzle (gridDim.x % 8 == 0 for all our launches)
    const int nwg = gridDim.x;
    const int wg = ((blockIdx.x & 7) * (nwg >> 3)) + (blockIdx.x >> 3);
    const int tiles_n = N >> 6;
    const int m0 = (wg / tiles_n) << 7;
    const int n0 = (wg % tiles_n) << 6;
    const int wv = tid >> 6, lane = tid & 63;
    const int lr = lane & 15, lg = lane >> 4;
    const int srow = lane >> 3;
    const int scb = ((lane & 7) ^ (lane >> 3)) << 3;

    f32x4 acc[2][4] = {};
    for (int kt = 0; kt < K; kt += 64) {
        __syncthreads();
#pragma unroll
        for (int i = 0; i < 4; i++) {
            int rbase = i * 32 + wv * 8;
            gload_lds16(A + (long)(m0 + rbase + srow) * K + kt + scb, As + rbase * 64);
        }
#pragma unroll
        for (int i = 0; i < 2; i++) {
            int rbase = i * 32 + wv * 8;
            gload_lds16(Bt + (long)(n0 + rbase + srow) * K + kt + scb, Bs + rbase * 64);
        }
        __syncthreads();
#pragma unroll
        for (int ks = 0; ks < 2; ks++) {
            bf16x8 af[2], bfv[4];
            int kb = (ks << 2) + lg;
#pragma unroll
            for (int mi = 0; mi < 2; mi++) {
                int r = (wv << 5) + (mi << 4) + lr;
                af[mi] = *(const bf16x8*)(As + r * 64 + ((kb ^ (r & 7)) << 3));
            }
#pragma unroll
            for (int ni = 0; ni < 4; ni++) {
                int r = (ni << 4) + lr;
                bfv[ni] = *(const bf16x8*)(Bs + r * 64 + ((kb ^ (r & 7)) << 3));
            }
#pragma unroll
            for (int mi = 0; mi < 2; mi++)
#pragma unroll
                for (int ni = 0; ni < 4; ni++)
                    acc[mi][ni] = __builtin_amdgcn_mfma_f32_16x16x32_bf16(
                        af[mi], bfv[ni], acc[mi][ni], 0, 0, 0);
        }
    }

#pragma unroll
    for (int mi = 0; mi < 2; mi++) {
        int rbase = m0 + (wv << 5) + (mi << 4) + (lg << 2);
#pragma unroll
        for (int ni = 0; ni < 4; ni++) {
            int col = n0 + (ni << 4) + lr;
            float bv = bias[col];
            if (MODE == 4) {
                float sc = 0.9999950000374997f * bng[col];
                float bb = bnb[col];
                f32x4 o;
#pragma unroll
                for (int e = 0; e < 4; e++) {
                    float v = (acc[mi][ni][e] + bv) * sc + bb;
                    o[e] = v > 0.f ? v : 0.f;
                }
                int b = rbase >> 15, l = rbase & 32767;
                *(f32x4*)(outF + ((long)(b * 192 + col) << 15) + l) = o;
            } else {
#pragma unroll
                for (int e = 0; e < 4; e++) {
                    int r = rbase + e;
                    float v = acc[mi][ni][e] + bv;
                    if (MODE == 0) {
                        outB[(long)r * N + col] = f2bf(v);
                    } else {  // MODE 3
                        int b = r >> 15, rr = r & 32767, widx = rr >> 6, n = rr & 63;
                        int wh = widx >> 6, ww = (widx >> 3) & 7, wt = widx & 7;
                        int ih = n >> 4, iw = (n >> 2) & 3, it = n & 3;
                        int h = ((wh << 2) + ih + shift) & 31;
                        int w = ((ww << 2) + iw + shift) & 31;
                        int t = ((wt << 2) + it + shift) & 31;
                        long tok = (long)(b << 15) + (h << 10) + (w << 5) + t;
                        resid[tok * 192 + col] += v;
                    }
                }
            }
        }
    }
}

// ---------------- fused MLP v2: resid += gelu(A @ W1 + b1) @ W2 + b2 ----------------
// Block = 128 rows (wave wv owns rows wv*32..+32), 12 hidden chunks of 64.
// A lives in REGISTERS (48 VGPR/lane, reused across all chunks).
// h exchange is wave-local -> only lgkmcnt, no barrier, between GEMM1 and GEMM2.
// LDS: W1 64x192 (24.5KB) + W2 192x64 (24.5KB) + Hs 128x64 (16KB) = 64KB -> 2 blocks/CU.
__global__ __launch_bounds__(256) void mlp_k(const short* __restrict__ A,
                                             const short* __restrict__ W1g,  // fc1T (768,192)
                                             const short* __restrict__ W2g,  // fc2T (192,768)
                                             const float* __restrict__ b1,
                                             const float* __restrict__ b2,
                                             float* __restrict__ resid) {
    __shared__ short W1s[12288];
    __shared__ short W2s[12288];
    __shared__ short Hs[8192];
    const int tid = threadIdx.x;
    const int wv = tid >> 6, lane = tid & 63;
    const int lr = lane & 15, lg = lane >> 4;
    const int mt = ((blockIdx.x & 7) << 6) + (blockIdx.x >> 3);  // XCD swizzle, 512 blocks
    const int m0 = mt << 7;

    // ---- A fragments straight into registers ----
    bf16x8 areg[2][6];
#pragma unroll
    for (int mi = 0; mi < 2; mi++)
#pragma unroll
        for (int kk = 0; kk < 6; kk++)
            areg[mi][kk] = *(const bf16x8*)(A + (long)(m0 + (wv << 5) + (mi << 4) + lr) * 192 + kk * 32 + (lg << 3));

    // ---- stage W chunk 0 ----
    bf16x8 w1r[6], w2r[6];
#pragma unroll
    for (int q = 0; q < 6; q++) {
        int f = q * 256 + tid;
        int r = f / 24, cb = f - r * 24;
        w1r[q] = *(const bf16x8*)(W1g + (long)r * 192 + cb * 8);
    }
#pragma unroll
    for (int q = 0; q < 6; q++) {
        int f = q * 256 + tid;
        int r = f >> 3, cb = f & 7;
        w2r[q] = *(const bf16x8*)(W2g + (long)r * 768 + cb * 8);
    }
#pragma unroll
    for (int q = 0; q < 6; q++) {
        int f = q * 256 + tid;
        int r = f / 24, cb = f - r * 24;
        *(bf16x8*)(W1s + r * 192 + ((cb ^ (r & 7)) << 3)) = w1r[q];
    }
#pragma unroll
    for (int q = 0; q < 6; q++) {
        int f = q * 256 + tid;
        int r = f >> 3, cb = f & 7;
        *(bf16x8*)(W2s + r * 64 + ((cb ^ (r & 7)) << 3)) = w2r[q];
    }
    __syncthreads();

    f32x4 acc[2][12] = {};

    for (int j = 0; j < 12; j++) {
        int jn = j < 11 ? j + 1 : 11;
        // prefetch W1(j+1) into regs (latency hidden under GEMM1)
#pragma unroll
        for (int q = 0; q < 6; q++) {
            int f = q * 256 + tid;
            int r = f / 24, cb = f - r * 24;
            w1r[q] = *(const bf16x8*)(W1g + (long)(jn * 64 + r) * 192 + cb * 8);
        }
        // ---- GEMM1: h = A @ W1(j)  (A in regs) ----
        f32x4 hacc[2][4] = {};
#pragma unroll
        for (int kk = 0; kk < 6; kk++) {
            int cb = (kk << 2) + lg;
            bf16x8 bf[4];
#pragma unroll
            for (int ni = 0; ni < 4; ni++) {
                int r = (ni << 4) + lr;
                bf[ni] = *(const bf16x8*)(W1s + r * 192 + ((cb ^ (r & 7)) << 3));
            }
#pragma unroll
            for (int mi = 0; mi < 2; mi++)
#pragma unroll
                for (int ni = 0; ni < 4; ni++)
                    hacc[mi][ni] = __builtin_amdgcn_mfma_f32_16x16x32_bf16(
                        areg[mi][kk], bf[ni], hacc[mi][ni], 0, 0, 0);
        }
        // prefetch W2(j+1) into regs (latency hidden under GELU + GEMM2)
#pragma unroll
        for (int q = 0; q < 6; q++) {
            int f = q * 256 + tid;
            int r = f >> 3, cb = f & 7;
            w2r[q] = *(const bf16x8*)(W2g + (long)r * 768 + jn * 64 + cb * 8);
        }
        // GELU(+b1) and write h to this wave's private Hs quarter
#pragma unroll
        for (int ni = 0; ni < 4; ni++) {
            float bv = b1[j * 64 + (ni << 4) + lr];
#pragma unroll
            for (int mi = 0; mi < 2; mi++)
#pragma unroll
                for (int e = 0; e < 4; e++) {
                    float v = hacc[mi][ni][e] + bv;
                    short hs = f2bf(0.5f * v * (1.f + erff(v * 0.70710678118654752f)));
                    int row = (wv << 5) + (mi << 4) + (lg << 2) + e;
                    int blk = (ni << 1) + (lr >> 3);
                    Hs[row * 64 + ((blk ^ (row & 7)) << 3) + (lr & 7)] = hs;
                }
        }
        // wave-local exchange: only need LDS queue drain, NOT a block barrier
        asm volatile("s_waitcnt lgkmcnt(0)" ::: "memory");
        // ---- GEMM2: acc += h(j) @ W2(j) ----
#pragma unroll
        for (int kk = 0; kk < 2; kk++) {
            int cb = (kk << 2) + lg;
            bf16x8 ah[2], bw[12];
#pragma unroll
            for (int mi = 0; mi < 2; mi++) {
                int r = (wv << 5) + (mi << 4) + lr;
                ah[mi] = *(const bf16x8*)(Hs + r * 64 + ((cb ^ (r & 7)) << 3));
            }
#pragma unroll
            for (int ni = 0; ni < 12; ni++) {
                int r = (ni << 4) + lr;
                bw[ni] = *(const bf16x8*)(W2s + r * 64 + ((cb ^ (r & 7)) << 3));
            }
#pragma unroll
            for (int mi = 0; mi < 2; mi++)
#pragma unroll
                for (int ni = 0; ni < 12; ni++)
                    acc[mi][ni] = __builtin_amdgcn_mfma_f32_16x16x32_bf16(
                        ah[mi], bw[ni], acc[mi][ni], 0, 0, 0);
        }
        __syncthreads();  // all waves done reading W1s(j)/W2s(j)
#pragma unroll
        for (int q = 0; q < 6; q++) {
            int f = q * 256 + tid;
            int r = f / 24, cb = f - r * 24;
            *(bf16x8*)(W1s + r * 192 + ((cb ^ (r & 7)) << 3)) = w1r[q];
        }
#pragma unroll
        for (int q = 0; q < 6; q++) {
            int f = q * 256 + tid;
            int r = f >> 3, cb = f & 7;
            *(bf16x8*)(W2s + r * 64 + ((cb ^ (r & 7)) << 3)) = w2r[q];
        }
        __syncthreads();  // W(j+1) staged
    }

    // ---- epilogue: resid += acc + b2 ----
#pragma unroll
    for (int mi = 0; mi < 2; mi++) {
        int rbase = m0 + (wv << 5) + (mi << 4) + (lg << 2);
#pragma unroll
        for (int ni = 0; ni < 12; ni++) {
            int col = (ni << 4) + lr;
            float bv = b2[col];
#pragma unroll
            for (int e = 0; e < 4; e++) {
                long r = rbase + e;
                resid[r * 192 + col] += acc[mi][ni][e] + bv;
            }
        }
    }
}

// ---------------- windowed attention: one wave per (window, head) ----------------
__global__ __launch_bounds__(256) void attn_k(const short* __restrict__ qkv,
                                              const float* __restrict__ rpb,  // (343,6)
                                              short* __restrict__ o, int shifted) {
    __shared__ short lds[4 * 6144];
    const int wv = threadIdx.x >> 6, lane = threadIdx.x & 63;
    short* vT = lds + wv * 6144;
    short* P = lds + wv * 6144 + 2048;
    const int task = blockIdx.x * 4 + wv;
    const int win = task / 6, head = task - win * 6;
    const int lr = lane & 15, lg = lane >> 4;
    const long qbase = (long)win * 64 * 576 + head * 32;

    bf16x8 aq[4], bk[4];
#pragma unroll
    for (int bi = 0; bi < 4; bi++)
        aq[bi] = *(const bf16x8*)(qkv + qbase + (long)((bi << 4) + lr) * 576 + (lg << 3));
#pragma unroll
    for (int bj = 0; bj < 4; bj++)
        bk[bj] = *(const bf16x8*)(qkv + qbase + 192 + (long)((bj << 4) + lr) * 576 + (lg << 3));
    f32x4 s[4][4] = {};
#pragma unroll
    for (int bi = 0; bi < 4; bi++)
#pragma unroll
        for (int bj = 0; bj < 4; bj++)
            s[bi][bj] = __builtin_amdgcn_mfma_f32_16x16x32_bf16(aq[bi], bk[bj], s[bi][bj], 0, 0, 0);

#pragma unroll
    for (int j = 0; j < 4; j++) {
        bf16x8 vv = *(const bf16x8*)(qkv + qbase + 384 + (long)lane * 576 + (j << 3));
#pragma unroll
        for (int e = 0; e < 8; e++) {
            int d = (j << 3) + e;
            vT[d * 64 + (((lane >> 3) ^ (d & 7)) << 3) + (lane & 7)] = vv[e];
        }
    }

    const float SCALE = 0.17677669529663687f;
    int widx = win & 511;
    int wh = widx >> 6, ww = (widx >> 3) & 7, wt = widx & 7;
    int ihm[4], iwm[4], itm[4], lblm[4];
#pragma unroll
    for (int bj = 0; bj < 4; bj++) {
        int m = (bj << 4) + lr;
        ihm[bj] = m >> 4; iwm[bj] = (m >> 2) & 3; itm[bj] = m & 3;
        lblm[bj] = reg3((wh << 2) + ihm[bj]) * 9 + reg3((ww << 2) + iwm[bj]) * 3 + reg3((wt << 2) + itm[bj]);
    }
#pragma unroll
    for (int bi = 0; bi < 4; bi++) {
#pragma unroll
        for (int e = 0; e < 4; e++) {
            int n = (bi << 4) + (lg << 2) + e;
            int ihn = n >> 4, iwn = (n >> 2) & 3, itn = n & 3;
            int lbln = reg3((wh << 2) + ihn) * 9 + reg3((ww << 2) + iwn) * 3 + reg3((wt << 2) + itn);
#pragma unroll
            for (int bj = 0; bj < 4; bj++) {
                int idx = (ihn - ihm[bj] + 3) * 49 + (iwn - iwm[bj] + 3) * 7 + (itn - itm[bj] + 3);
                float bias = rpb[idx * 6 + head];
                float val = s[bi][bj][e] * SCALE + bias;
                if (shifted && lbln != lblm[bj]) val -= 100.f;
                s[bi][bj][e] = val;
            }
        }
    }

#pragma unroll
    for (int bi = 0; bi < 4; bi++) {
#pragma unroll
        for (int e = 0; e < 4; e++) {
            float mx = s[bi][0][e];
#pragma unroll
            for (int bj = 1; bj < 4; bj++) mx = fmaxf(mx, s[bi][bj][e]);
#pragma unroll
            for (int off = 1; off < 16; off <<= 1) mx = fmaxf(mx, __shfl_xor(mx, off, 64));
            float sm = 0.f;
#pragma unroll
            for (int bj = 0; bj < 4; bj++) {
                float p = __expf(s[bi][bj][e] - mx);
                s[bi][bj][e] = p;
                sm += p;
            }
#pragma unroll
            for (int off = 1; off < 16; off <<= 1) sm += __shfl_xor(sm, off, 64);
            float rinv = 1.f / sm;
            int n = (bi << 4) + (lg << 2) + e;
#pragma unroll
            for (int bj = 0; bj < 4; bj++) {
                int m = (bj << 4) + lr;
                P[n * 64 + (((m >> 3) ^ (n & 7)) << 3) + (m & 7)] = f2bf(s[bi][bj][e] * rinv);
            }
        }
    }

    f32x4 oacc[4][2] = {};
#pragma unroll
    for (int ks = 0; ks < 2; ks++) {
        bf16x8 ap[4], bv2[2];
        int kb = (ks << 2) + lg;
#pragma unroll
        for (int bi = 0; bi < 4; bi++) {
            int r = (bi << 4) + lr;
            ap[bi] = *(const bf16x8*)(P + r * 64 + ((kb ^ (r & 7)) << 3));
        }
#pragma unroll
        for (int nf = 0; nf < 2; nf++) {
            int d = (nf << 4) + lr;
            bv2[nf] = *(const bf16x8*)(vT + d * 64 + ((kb ^ (d & 7)) << 3));
        }
#pragma unroll
        for (int bi = 0; bi < 4; bi++)
#pragma unroll
            for (int nf = 0; nf < 2; nf++)
                oacc[bi][nf] = __builtin_amdgcn_mfma_f32_16x16x32_bf16(ap[bi], bv2[nf], oacc[bi][nf], 0, 0, 0);
    }
#pragma unroll
    for (int bi = 0; bi < 4; bi++)
#pragma unroll
        for (int nf = 0; nf < 2; nf++)
#pragma unroll
            for (int e = 0; e < 4; e++) {
                int n = (bi << 4) + (lg << 2) + e;
                int d = (nf << 4) + lr;
                o[((long)win * 64 + n) * 192 + head * 32 + d] = f2bf(oacc[bi][nf][e]);
            }
}

// ---------------- depthwise 3x3x3 conv, register-blocked along t ----------------
__global__ __launch_bounds__(192) void dw_k(const float* __restrict__ xf,
                                            const float* __restrict__ w,
                                            const float* __restrict__ db,
                                            short* __restrict__ out) {
    int c = threadIdx.x;
    int blk = blockIdx.x;
    int t0 = (blk & 3) << 3;
    int bhw = blk >> 2;
    int b = bhw >> 10, h = (bhw >> 5) & 31, wq = bhw & 31;

    float wr[27];
#pragma unroll
    for (int k = 0; k < 27; k++) wr[k] = w[c * 27 + k];
    float bias = db[c];
    float acc[8];
#pragma unroll
    for (int j = 0; j < 8; j++) acc[j] = bias;

#pragma unroll
    for (int a = 0; a < 3; a++) {
        int hh = h + a - 1;
        if (hh < 0 || hh > 31) continue;
#pragma unroll
        for (int bb = 0; bb < 3; bb++) {
            int ww = wq + bb - 1;
            if (ww < 0 || ww > 31) continue;
            const float* base = xf + ((long)(b << 15) + (hh << 10) + (ww << 5)) * 192 + c;
            float val[10];
#pragma unroll
            for (int tt = 0; tt < 10; tt++) {
                int t = t0 + tt - 1;
                val[tt] = (t >= 0 && t < 32) ? base[t * 192] : 0.f;
            }
#pragma unroll
            for (int d = 0; d < 3; d++) {
                float wv = wr[a * 9 + bb * 3 + d];
#pragma unroll
                for (int j = 0; j < 8; j++)
                    acc[j] = fmaf(val[j + d], wv, acc[j]);
            }
        }
    }
    long obase = ((long)(b << 15) + (h << 10) + (wq << 5) + t0) * 192 + c;
#pragma unroll
    for (int j = 0; j < 8; j++) out[obase + j * 192] = f2bf(acc[j]);
}

// ---------------- launch ----------------
extern "C" void kernel_launch(void* const* d_in, const int* in_sizes, int n_in,
                              void* d_out, int out_size, void* d_ws, size_t ws_size,
                              hipStream_t stream) {
    const float* x      = (const float*)d_in[0];
    const float* n1g    = (const float*)d_in[1];
    const float* n1b    = (const float*)d_in[2];
    const float* qkv_w  = (const float*)d_in[3];
    const float* qkv_b  = (const float*)d_in[4];
    const float* rpb    = (const float*)d_in[5];
    const float* proj_w = (const float*)d_in[6];
    const float* proj_b = (const float*)d_in[7];
    const float* n2g    = (const float*)d_in[8];
    const float* n2b    = (const float*)d_in[9];
    const float* fc1_w  = (const float*)d_in[10];
    const float* fc1_b  = (const float*)d_in[11];
    const float* fc2_w  = (const float*)d_in[12];
    const float* fc2_b  = (const float*)d_in[13];
    const float* dw_w   = (const float*)d_in[14];
    const float* dw_b   = (const float*)d_in[15];
    const float* pw_w   = (const float*)d_in[16];
    const float* pw_b   = (const float*)d_in[17];
    const float* bn_g   = (const float*)d_in[18];
    const float* bn_b   = (const float*)d_in[19];
    float* outF = (float*)d_out;

    char* ws = (char*)d_ws;
    float* XF = (float*)ws;
    short* Abuf = (short*)(ws + 50331648);
    short* Bbuf = (short*)(ws + 150994944);
    short* WT = (short*)(ws + 226492416);

    transpose_in<<<dim3(1024, 6, 2), dim3(32, 8), 0, stream>>>(x, XF);
    prep_w<<<7056, 256, 0, stream>>>(qkv_w, proj_w, fc1_w, fc2_w, pw_w, WT);

    for (int i = 0; i < 4; i++) {
        int shifted = i & 1;
        int shift = shifted ? 2 : 0;
        ln_k<true><<<16384, 256, 0, stream>>>(XF, n1g + i * 192, n1b + i * 192, Abuf, shift);
        gemm_k<0><<<4608, 256, 0, stream>>>(Abuf, WT + (long)i * 442368, qkv_b + i * 576,
                                            Bbuf, nullptr, nullptr, nullptr, nullptr,
                                            65536, 576, 192, 0);
        attn_k<<<1536, 256, 0, stream>>>(Bbuf, rpb + i * 2058, Abuf, shifted);
        gemm_k<3><<<1536, 256, 0, stream>>>(Abuf, WT + (long)i * 442368 + 110592, proj_b + i * 192,
                                            nullptr, XF, nullptr, nullptr, nullptr,
                                            65536, 192, 192, shift);
        ln_k<false><<<16384, 256, 0, stream>>>(XF, n2g + i * 192, n2b + i * 192, Bbuf, 0);
        mlp_k<<<512, 256, 0, stream>>>(Bbuf, WT + (long)i * 442368 + 147456,
                                       WT + (long)i * 442368 + 294912,
                                       fc1_b + i * 768, fc2_b + i * 192, XF);
    }

    dw_k<<<8192, 192, 0, stream>>>(XF, dw_w, dw_b, Abuf);
    gemm_k<4><<<1536, 256, 0, stream>>>(Abuf, WT + 1769472, pw_b,
                                        nullptr, nullptr, outF, bn_g, bn_b,
                                        65536, 192, 192, 0);
}

// Round 6
// 952.237 us; speedup vs baseline: 1.0856x; 1.0650x over previous
//
#include <hip/hip_runtime.h>
#include <hip/hip_bf16.h>

// ---------------- constants ----------------
// C=192, H=W=T=32, WS=4, SS=2, NH=6, HD=32, N=64 tokens/window
// L = 32768 tokens/batch, B=2 -> M = 65536 rows everywhere.
#define DI __device__ __forceinline__

typedef short bf16x8 __attribute__((ext_vector_type(8)));
typedef float f32x4 __attribute__((ext_vector_type(4)));

DI short f2bf(float f) {
    __hip_bfloat16 h = __float2bfloat16(f);
    return *reinterpret_cast<short*>(&h);
}

DI void gload_lds16(const short* gsrc, short* ldst) {
    __builtin_amdgcn_global_load_lds(
        (const __attribute__((address_space(1))) void*)gsrc,
        (__attribute__((address_space(3))) void*)ldst, 16, 0, 0);
}

// region label along one axis for the shift mask: [0,28)->0, [28,30)->1, [30,32)->2
DI int reg3(int p) { return p < 28 ? 0 : (p < 30 ? 1 : 2); }

// ---------------- input transpose: x (B,C,L) -> xf (B,L,C) f32 ----------------
__global__ __launch_bounds__(256) void transpose_in(const float* __restrict__ x,
                                                    float* __restrict__ xf) {
    __shared__ float tile[32][33];
    int b = blockIdx.z;
    int c0 = blockIdx.y * 32;
    int l0 = blockIdx.x * 32;
    int tx = threadIdx.x, ty = threadIdx.y;  // 32 x 8
#pragma unroll
    for (int i = 0; i < 32; i += 8)
        tile[ty + i][tx] = x[(long)(b * 192 + c0 + ty + i) * 32768 + l0 + tx];
    __syncthreads();
#pragma unroll
    for (int i = 0; i < 32; i += 8)
        xf[(long)(b * 32768 + l0 + ty + i) * 192 + c0 + tx] = tile[tx][ty + i];
}

// ---------------- weight prep ----------------
__global__ __launch_bounds__(256) void prep_w(const float* __restrict__ qkv_w,
                                              const float* __restrict__ proj_w,
                                              const float* __restrict__ fc1_w,
                                              const float* __restrict__ fc2_w,
                                              const float* __restrict__ pw_w,
                                              short* __restrict__ wt) {
    int i = blockIdx.x * 256 + threadIdx.x;
    float v;
    if (i < 1769472) {
        int b4 = i / 442368, r = i - b4 * 442368;
        if (r < 110592) { int n = r / 192, k = r - n * 192; v = qkv_w[b4 * 110592 + k * 576 + n]; }
        else if (r < 147456) { int r2 = r - 110592; int n = r2 / 192, k = r2 - n * 192; v = proj_w[b4 * 36864 + k * 192 + n]; }
        else if (r < 294912) { int r2 = r - 147456; int n = r2 / 192, k = r2 - n * 192; v = fc1_w[b4 * 147456 + k * 768 + n]; }
        else { int r2 = r - 294912; int n = r2 / 768, k = r2 - n * 768; v = fc2_w[b4 * 147456 + k * 192 + n]; }
        wt[i] = f2bf(v);
    } else {
        int r = i - 1769472;
        wt[i] = f2bf(pw_w[r]);
    }
}

// ---------------- LayerNorm (wave per token) fused roll+window-partition (LN1) ----------------
template <bool PART>
__global__ __launch_bounds__(256) void ln_k(const float* __restrict__ xf,
                                            const float* __restrict__ g,
                                            const float* __restrict__ bta,
                                            short* __restrict__ out, int shift) {
    int wv = threadIdx.x >> 6, lane = threadIdx.x & 63;
    int row = blockIdx.x * 4 + wv;
    long src;
    if (PART) {
        int b = row >> 15, r = row & 32767, widx = r >> 6, n = r & 63;
        int wh = widx >> 6, ww = (widx >> 3) & 7, wt = widx & 7;
        int ih = n >> 4, iw = (n >> 2) & 3, it = n & 3;
        int h = ((wh << 2) + ih + shift) & 31;
        int w = ((ww << 2) + iw + shift) & 31;
        int t = ((wt << 2) + it + shift) & 31;
        src = ((long)(b << 15) + (h << 10) + (w << 5) + t) * 192;
    } else {
        src = (long)row * 192;
    }
    float v[3], s = 0.f, sq = 0.f;
#pragma unroll
    for (int j = 0; j < 3; j++) {
        v[j] = xf[src + lane + 64 * j];
        s += v[j];
        sq += v[j] * v[j];
    }
#pragma unroll
    for (int o = 1; o < 64; o <<= 1) {
        s += __shfl_xor(s, o, 64);
        sq += __shfl_xor(sq, o, 64);
    }
    float mu = s * (1.f / 192.f);
    float var = sq * (1.f / 192.f) - mu * mu;
    float rstd = rsqrtf(var + 1e-5f);
    long dst = (long)row * 192;
#pragma unroll
    for (int j = 0; j < 3; j++) {
        int c = lane + 64 * j;
        out[dst + c] = f2bf((v[j] - mu) * rstd * g[c] + bta[c]);
    }
}

// ---------------- generic bf16 MFMA GEMM: out(M,N) = A(M,K) @ Bt(N,K)^T + bias ----------------
// MODE 0: out bf16   MODE 3: window-reverse+roll -> resid += v (proj)
// MODE 4: pointwise conv epilogue: BN + ReLU, write f32 channel-major output
template <int MODE>
__global__ __launch_bounds__(256) void gemm_k(
    const short* __restrict__ A, const short* __restrict__ Bt,
    const float* __restrict__ bias,
    short* __restrict__ outB, float* __restrict__ resid, float* __restrict__ outF,
    const float* __restrict__ bng, const float* __restrict__ bnb,
    int M, int N, int K, int shift) {
    __shared__ short As[128 * 64];
    __shared__ short Bs[64 * 64];
    const int tid = threadIdx.x;
    // bijective XCD-chunked swizzle (gridDim.x % 8 == 0 for all our launches)
    const int nwg = gridDim.x;
    const int wg = ((blockIdx.x & 7) * (nwg >> 3)) + (blockIdx.x >> 3);
    const int tiles_n = N >> 6;
    const int m0 = (wg / tiles_n) << 7;
    const int n0 = (wg % tiles_n) << 6;
    const int wv = tid >> 6, lane = tid & 63;
    const int lr = lane & 15, lg = lane >> 4;
    const int srow = lane >> 3;
    const int scb = ((lane & 7) ^ (lane >> 3)) << 3;

    f32x4 acc[2][4] = {};
    for (int kt = 0; kt < K; kt += 64) {
        __syncthreads();
#pragma unroll
        for (int i = 0; i < 4; i++) {
            int rbase = i * 32 + wv * 8;
            gload_lds16(A + (long)(m0 + rbase + srow) * K + kt + scb, As + rbase * 64);
        }
#pragma unroll
        for (int i = 0; i < 2; i++) {
            int rbase = i * 32 + wv * 8;
            gload_lds16(Bt + (long)(n0 + rbase + srow) * K + kt + scb, Bs + rbase * 64);
        }
        __syncthreads();
#pragma unroll
        for (int ks = 0; ks < 2; ks++) {
            bf16x8 af[2], bfv[4];
            int kb = (ks << 2) + lg;
#pragma unroll
            for (int mi = 0; mi < 2; mi++) {
                int r = (wv << 5) + (mi << 4) + lr;
                af[mi] = *(const bf16x8*)(As + r * 64 + ((kb ^ (r & 7)) << 3));
            }
#pragma unroll
            for (int ni = 0; ni < 4; ni++) {
                int r = (ni << 4) + lr;
                bfv[ni] = *(const bf16x8*)(Bs + r * 64 + ((kb ^ (r & 7)) << 3));
            }
#pragma unroll
            for (int mi = 0; mi < 2; mi++)
#pragma unroll
                for (int ni = 0; ni < 4; ni++)
                    acc[mi][ni] = __builtin_amdgcn_mfma_f32_16x16x32_bf16(
                        af[mi], bfv[ni], acc[mi][ni], 0, 0, 0);
        }
    }

#pragma unroll
    for (int mi = 0; mi < 2; mi++) {
        int rbase = m0 + (wv << 5) + (mi << 4) + (lg << 2);
#pragma unroll
        for (int ni = 0; ni < 4; ni++) {
            int col = n0 + (ni << 4) + lr;
            float bv = bias[col];
            if (MODE == 4) {
                float sc = 0.9999950000374997f * bng[col];
                float bb = bnb[col];
                f32x4 o;
#pragma unroll
                for (int e = 0; e < 4; e++) {
                    float v = (acc[mi][ni][e] + bv) * sc + bb;
                    o[e] = v > 0.f ? v : 0.f;
                }
                int b = rbase >> 15, l = rbase & 32767;
                *(f32x4*)(outF + ((long)(b * 192 + col) << 15) + l) = o;
            } else {
#pragma unroll
                for (int e = 0; e < 4; e++) {
                    int r = rbase + e;
                    float v = acc[mi][ni][e] + bv;
                    if (MODE == 0) {
                        outB[(long)r * N + col] = f2bf(v);
                    } else {  // MODE 3
                        int b = r >> 15, rr = r & 32767, widx = rr >> 6, n = rr & 63;
                        int wh = widx >> 6, ww = (widx >> 3) & 7, wt = widx & 7;
                        int ih = n >> 4, iw = (n >> 2) & 3, it = n & 3;
                        int h = ((wh << 2) + ih + shift) & 31;
                        int w = ((ww << 2) + iw + shift) & 31;
                        int t = ((wt << 2) + it + shift) & 31;
                        long tok = (long)(b << 15) + (h << 10) + (w << 5) + t;
                        resid[tok * 192 + col] += v;
                    }
                }
            }
        }
    }
}

// ---------------- fused LN2 + MLP v3: resid += gelu(LN(x) @ W1 + b1) @ W2 + b2 ----------------
// Block = 128 rows (wave wv owns rows wv*32..+32), 12 hidden chunks of 64.
// LN2 computed in the prologue (row spans 4 lanes -> 2 shfl_xor).
// GELU via tanh-form sigmoid (HW v_exp_f32), not erff.
// LDS: W1 64x192 (24.5KB) + W2 192x64 (24.5KB) + Hs 128x64 (16KB) = 64KB.
__global__ __launch_bounds__(256) void mlp_k(const float* __restrict__ XF,
                                             const short* __restrict__ W1g,  // fc1T (768,192)
                                             const short* __restrict__ W2g,  // fc2T (192,768)
                                             const float* __restrict__ b1,
                                             const float* __restrict__ b2,
                                             const float* __restrict__ n2g,
                                             const float* __restrict__ n2b,
                                             float* __restrict__ resid) {
    __shared__ short W1s[12288];
    __shared__ short W2s[12288];
    __shared__ short Hs[8192];
    const int tid = threadIdx.x;
    const int wv = tid >> 6, lane = tid & 63;
    const int lr = lane & 15, lg = lane >> 4;
    const int mt = ((blockIdx.x & 7) << 6) + (blockIdx.x >> 3);  // XCD swizzle, 512 blocks
    const int m0 = mt << 7;

    // ---- LN2 prologue: x rows -> normalized bf16 A fragments in registers ----
    bf16x8 areg[2][6];
#pragma unroll
    for (int mi = 0; mi < 2; mi++) {
        const float* rp = XF + (long)(m0 + (wv << 5) + (mi << 4) + lr) * 192;
        f32x4 xv[6][2];
        float s = 0.f, sq = 0.f;
#pragma unroll
        for (int kk = 0; kk < 6; kk++)
#pragma unroll
            for (int q = 0; q < 2; q++) {
                xv[kk][q] = *(const f32x4*)(rp + kk * 32 + (lg << 3) + q * 4);
#pragma unroll
                for (int e = 0; e < 4; e++) {
                    s += xv[kk][q][e];
                    sq += xv[kk][q][e] * xv[kk][q][e];
                }
            }
        // row spans lanes with same lr across lg=0..3 (lane bits 4-5)
        s += __shfl_xor(s, 16, 64); s += __shfl_xor(s, 32, 64);
        sq += __shfl_xor(sq, 16, 64); sq += __shfl_xor(sq, 32, 64);
        float mu = s * (1.f / 192.f);
        float var = sq * (1.f / 192.f) - mu * mu;
        float rstd = rsqrtf(var + 1e-5f);
#pragma unroll
        for (int kk = 0; kk < 6; kk++) {
            int cb = kk * 32 + (lg << 3);
            f32x4 g0 = *(const f32x4*)(n2g + cb), g1 = *(const f32x4*)(n2g + cb + 4);
            f32x4 b0 = *(const f32x4*)(n2b + cb), b1v = *(const f32x4*)(n2b + cb + 4);
            bf16x8 t;
#pragma unroll
            for (int e = 0; e < 4; e++) {
                t[e] = f2bf((xv[kk][0][e] - mu) * rstd * g0[e] + b0[e]);
                t[e + 4] = f2bf((xv[kk][1][e] - mu) * rstd * g1[e] + b1v[e]);
            }
            areg[mi][kk] = t;
        }
    }

    // ---- stage W chunk 0 ----
    bf16x8 w1r[6], w2r[6];
#pragma unroll
    for (int q = 0; q < 6; q++) {
        int f = q * 256 + tid;
        int r = f / 24, cb = f - r * 24;
        w1r[q] = *(const bf16x8*)(W1g + (long)r * 192 + cb * 8);
    }
#pragma unroll
    for (int q = 0; q < 6; q++) {
        int f = q * 256 + tid;
        int r = f >> 3, cb = f & 7;
        w2r[q] = *(const bf16x8*)(W2g + (long)r * 768 + cb * 8);
    }
#pragma unroll
    for (int q = 0; q < 6; q++) {
        int f = q * 256 + tid;
        int r = f / 24, cb = f - r * 24;
        *(bf16x8*)(W1s + r * 192 + ((cb ^ (r & 7)) << 3)) = w1r[q];
    }
#pragma unroll
    for (int q = 0; q < 6; q++) {
        int f = q * 256 + tid;
        int r = f >> 3, cb = f & 7;
        *(bf16x8*)(W2s + r * 64 + ((cb ^ (r & 7)) << 3)) = w2r[q];
    }
    __syncthreads();

    f32x4 acc[2][12] = {};

    for (int j = 0; j < 12; j++) {
        int jn = j < 11 ? j + 1 : 11;
        // prefetch W1(j+1) into regs (latency hidden under GEMM1)
#pragma unroll
        for (int q = 0; q < 6; q++) {
            int f = q * 256 + tid;
            int r = f / 24, cb = f - r * 24;
            w1r[q] = *(const bf16x8*)(W1g + (long)(jn * 64 + r) * 192 + cb * 8);
        }
        // ---- GEMM1: h = A @ W1(j)  (A in regs) ----
        f32x4 hacc[2][4] = {};
#pragma unroll
        for (int kk = 0; kk < 6; kk++) {
            int cb = (kk << 2) + lg;
            bf16x8 bf[4];
#pragma unroll
            for (int ni = 0; ni < 4; ni++) {
                int r = (ni << 4) + lr;
                bf[ni] = *(const bf16x8*)(W1s + r * 192 + ((cb ^ (r & 7)) << 3));
            }
#pragma unroll
            for (int mi = 0; mi < 2; mi++)
#pragma unroll
                for (int ni = 0; ni < 4; ni++)
                    hacc[mi][ni] = __builtin_amdgcn_mfma_f32_16x16x32_bf16(
                        areg[mi][kk], bf[ni], hacc[mi][ni], 0, 0, 0);
        }
        // prefetch W2(j+1) into regs (latency hidden under GELU + GEMM2)
#pragma unroll
        for (int q = 0; q < 6; q++) {
            int f = q * 256 + tid;
            int r = f >> 3, cb = f & 7;
            w2r[q] = *(const bf16x8*)(W2g + (long)r * 768 + jn * 64 + cb * 8);
        }
        // fast GELU(+b1) and write h to this wave's private Hs quarter
#pragma unroll
        for (int ni = 0; ni < 4; ni++) {
            float bv = b1[j * 64 + (ni << 4) + lr];
#pragma unroll
            for (int mi = 0; mi < 2; mi++)
#pragma unroll
                for (int e = 0; e < 4; e++) {
                    float v = hacc[mi][ni][e] + bv;
                    float u = v * (0.7978845608f + 0.03567740814f * v * v);
                    float gl = v / (1.f + __expf(-2.f * u));
                    short hs = f2bf(gl);
                    int row = (wv << 5) + (mi << 4) + (lg << 2) + e;
                    int blk = (ni << 1) + (lr >> 3);
                    Hs[row * 64 + ((blk ^ (row & 7)) << 3) + (lr & 7)] = hs;
                }
        }
        // wave-local exchange: only need LDS queue drain, NOT a block barrier
        asm volatile("s_waitcnt lgkmcnt(0)" ::: "memory");
        // ---- GEMM2: acc += h(j) @ W2(j) ----
#pragma unroll
        for (int kk = 0; kk < 2; kk++) {
            int cb = (kk << 2) + lg;
            bf16x8 ah[2], bw[12];
#pragma unroll
            for (int mi = 0; mi < 2; mi++) {
                int r = (wv << 5) + (mi << 4) + lr;
                ah[mi] = *(const bf16x8*)(Hs + r * 64 + ((cb ^ (r & 7)) << 3));
            }
#pragma unroll
            for (int ni = 0; ni < 12; ni++) {
                int r = (ni << 4) + lr;
                bw[ni] = *(const bf16x8*)(W2s + r * 64 + ((cb ^ (r & 7)) << 3));
            }
#pragma unroll
            for (int mi = 0; mi < 2; mi++)
#pragma unroll
                for (int ni = 0; ni < 12; ni++)
                    acc[mi][ni] = __builtin_amdgcn_mfma_f32_16x16x32_bf16(
                        ah[mi], bw[ni], acc[mi][ni], 0, 0, 0);
        }
        __syncthreads();  // all waves done reading W1s(j)/W2s(j)
#pragma unroll
        for (int q = 0; q < 6; q++) {
            int f = q * 256 + tid;
            int r = f / 24, cb = f - r * 24;
            *(bf16x8*)(W1s + r * 192 + ((cb ^ (r & 7)) << 3)) = w1r[q];
        }
#pragma unroll
        for (int q = 0; q < 6; q++) {
            int f = q * 256 + tid;
            int r = f >> 3, cb = f & 7;
            *(bf16x8*)(W2s + r * 64 + ((cb ^ (r & 7)) << 3)) = w2r[q];
        }
        __syncthreads();  // W(j+1) staged
    }

    // ---- epilogue: resid += acc + b2 ----
#pragma unroll
    for (int mi = 0; mi < 2; mi++) {
        int rbase = m0 + (wv << 5) + (mi << 4) + (lg << 2);
#pragma unroll
        for (int ni = 0; ni < 12; ni++) {
            int col = (ni << 4) + lr;
            float bv = b2[col];
#pragma unroll
            for (int e = 0; e < 4; e++) {
                long r = rbase + e;
                resid[r * 192 + col] += acc[mi][ni][e] + bv;
            }
        }
    }
}

// ---------------- windowed attention: one wave per (window, head) ----------------
__global__ __launch_bounds__(256) void attn_k(const short* __restrict__ qkv,
                                              const float* __restrict__ rpb,  // (343,6)
                                              short* __restrict__ o, int shifted) {
    __shared__ short lds[4 * 6144];
    const int wv = threadIdx.x >> 6, lane = threadIdx.x & 63;
    short* vT = lds + wv * 6144;
    short* P = lds + wv * 6144 + 2048;
    const int task = blockIdx.x * 4 + wv;
    const int win = task / 6, head = task - win * 6;
    const int lr = lane & 15, lg = lane >> 4;
    const long qbase = (long)win * 64 * 576 + head * 32;

    bf16x8 aq[4], bk[4];
#pragma unroll
    for (int bi = 0; bi < 4; bi++)
        aq[bi] = *(const bf16x8*)(qkv + qbase + (long)((bi << 4) + lr) * 576 + (lg << 3));
#pragma unroll
    for (int bj = 0; bj < 4; bj++)
        bk[bj] = *(const bf16x8*)(qkv + qbase + 192 + (long)((bj << 4) + lr) * 576 + (lg << 3));
    f32x4 s[4][4] = {};
#pragma unroll
    for (int bi = 0; bi < 4; bi++)
#pragma unroll
        for (int bj = 0; bj < 4; bj++)
            s[bi][bj] = __builtin_amdgcn_mfma_f32_16x16x32_bf16(aq[bi], bk[bj], s[bi][bj], 0, 0, 0);

#pragma unroll
    for (int j = 0; j < 4; j++) {
        bf16x8 vv = *(const bf16x8*)(qkv + qbase + 384 + (long)lane * 576 + (j << 3));
#pragma unroll
        for (int e = 0; e < 8; e++) {
            int d = (j << 3) + e;
            vT[d * 64 + (((lane >> 3) ^ (d & 7)) << 3) + (lane & 7)] = vv[e];
        }
    }

    const float SCALE = 0.17677669529663687f;
    int widx = win & 511;
    int wh = widx >> 6, ww = (widx >> 3) & 7, wt = widx & 7;
    int ihm[4], iwm[4], itm[4], lblm[4];
#pragma unroll
    for (int bj = 0; bj < 4; bj++) {
        int m = (bj << 4) + lr;
        ihm[bj] = m >> 4; iwm[bj] = (m >> 2) & 3; itm[bj] = m & 3;
        lblm[bj] = reg3((wh << 2) + ihm[bj]) * 9 + reg3((ww << 2) + iwm[bj]) * 3 + reg3((wt << 2) + itm[bj]);
    }
#pragma unroll
    for (int bi = 0; bi < 4; bi++) {
#pragma unroll
        for (int e = 0; e < 4; e++) {
            int n = (bi << 4) + (lg << 2) + e;
            int ihn = n >> 4, iwn = (n >> 2) & 3, itn = n & 3;
            int lbln = reg3((wh << 2) + ihn) * 9 + reg3((ww << 2) + iwn) * 3 + reg3((wt << 2) + itn);
#pragma unroll
            for (int bj = 0; bj < 4; bj++) {
                int idx = (ihn - ihm[bj] + 3) * 49 + (iwn - iwm[bj] + 3) * 7 + (itn - itm[bj] + 3);
                float bias = rpb[idx * 6 + head];
                float val = s[bi][bj][e] * SCALE + bias;
                if (shifted && lbln != lblm[bj]) val -= 100.f;
                s[bi][bj][e] = val;
            }
        }
    }

#pragma unroll
    for (int bi = 0; bi < 4; bi++) {
#pragma unroll
        for (int e = 0; e < 4; e++) {
            float mx = s[bi][0][e];
#pragma unroll
            for (int bj = 1; bj < 4; bj++) mx = fmaxf(mx, s[bi][bj][e]);
#pragma unroll
            for (int off = 1; off < 16; off <<= 1) mx = fmaxf(mx, __shfl_xor(mx, off, 64));
            float sm = 0.f;
#pragma unroll
            for (int bj = 0; bj < 4; bj++) {
                float p = __expf(s[bi][bj][e] - mx);
                s[bi][bj][e] = p;
                sm += p;
            }
#pragma unroll
            for (int off = 1; off < 16; off <<= 1) sm += __shfl_xor(sm, off, 64);
            float rinv = 1.f / sm;
            int n = (bi << 4) + (lg << 2) + e;
#pragma unroll
            for (int bj = 0; bj < 4; bj++) {
                int m = (bj << 4) + lr;
                P[n * 64 + (((m >> 3) ^ (n & 7)) << 3) + (m & 7)] = f2bf(s[bi][bj][e] * rinv);
            }
        }
    }

    f32x4 oacc[4][2] = {};
#pragma unroll
    for (int ks = 0; ks < 2; ks++) {
        bf16x8 ap[4], bv2[2];
        int kb = (ks << 2) + lg;
#pragma unroll
        for (int bi = 0; bi < 4; bi++) {
            int r = (bi << 4) + lr;
            ap[bi] = *(const bf16x8*)(P + r * 64 + ((kb ^ (r & 7)) << 3));
        }
#pragma unroll
        for (int nf = 0; nf < 2; nf++) {
            int d = (nf << 4) + lr;
            bv2[nf] = *(const bf16x8*)(vT + d * 64 + ((kb ^ (d & 7)) << 3));
        }
#pragma unroll
        for (int bi = 0; bi < 4; bi++)
#pragma unroll
            for (int nf = 0; nf < 2; nf++)
                oacc[bi][nf] = __builtin_amdgcn_mfma_f32_16x16x32_bf16(ap[bi], bv2[nf], oacc[bi][nf], 0, 0, 0);
    }
#pragma unroll
    for (int bi = 0; bi < 4; bi++)
#pragma unroll
        for (int nf = 0; nf < 2; nf++)
#pragma unroll
            for (int e = 0; e < 4; e++) {
                int n = (bi << 4) + (lg << 2) + e;
                int d = (nf << 4) + lr;
                o[((long)win * 64 + n) * 192 + head * 32 + d] = f2bf(oacc[bi][nf][e]);
            }
}

// ---------------- depthwise 3x3x3 conv, register-blocked along t ----------------
__global__ __launch_bounds__(192) void dw_k(const float* __restrict__ xf,
                                            const float* __restrict__ w,
                                            const float* __restrict__ db,
                                            short* __restrict__ out) {
    int c = threadIdx.x;
    int blk = blockIdx.x;
    int t0 = (blk & 3) << 3;
    int bhw = blk >> 2;
    int b = bhw >> 10, h = (bhw >> 5) & 31, wq = bhw & 31;

    float wr[27];
#pragma unroll
    for (int k = 0; k < 27; k++) wr[k] = w[c * 27 + k];
    float bias = db[c];
    float acc[8];
#pragma unroll
    for (int j = 0; j < 8; j++) acc[j] = bias;

#pragma unroll
    for (int a = 0; a < 3; a++) {
        int hh = h + a - 1;
        if (hh < 0 || hh > 31) continue;
#pragma unroll
        for (int bb = 0; bb < 3; bb++) {
            int ww = wq + bb - 1;
            if (ww < 0 || ww > 31) continue;
            const float* base = xf + ((long)(b << 15) + (hh << 10) + (ww << 5)) * 192 + c;
            float val[10];
#pragma unroll
            for (int tt = 0; tt < 10; tt++) {
                int t = t0 + tt - 1;
                val[tt] = (t >= 0 && t < 32) ? base[t * 192] : 0.f;
            }
#pragma unroll
            for (int d = 0; d < 3; d++) {
                float wv = wr[a * 9 + bb * 3 + d];
#pragma unroll
                for (int j = 0; j < 8; j++)
                    acc[j] = fmaf(val[j + d], wv, acc[j]);
            }
        }
    }
    long obase = ((long)(b << 15) + (h << 10) + (wq << 5) + t0) * 192 + c;
#pragma unroll
    for (int j = 0; j < 8; j++) out[obase + j * 192] = f2bf(acc[j]);
}

// ---------------- launch ----------------
extern "C" void kernel_launch(void* const* d_in, const int* in_sizes, int n_in,
                              void* d_out, int out_size, void* d_ws, size_t ws_size,
                              hipStream_t stream) {
    const float* x      = (const float*)d_in[0];
    const float* n1g    = (const float*)d_in[1];
    const float* n1b    = (const float*)d_in[2];
    const float* qkv_w  = (const float*)d_in[3];
    const float* qkv_b  = (const float*)d_in[4];
    const float* rpb    = (const float*)d_in[5];
    const float* proj_w = (const float*)d_in[6];
    const float* proj_b = (const float*)d_in[7];
    const float* n2g    = (const float*)d_in[8];
    const float* n2b    = (const float*)d_in[9];
    const float* fc1_w  = (const float*)d_in[10];
    const float* fc1_b  = (const float*)d_in[11];
    const float* fc2_w  = (const float*)d_in[12];
    const float* fc2_b  = (const float*)d_in[13];
    const float* dw_w   = (const float*)d_in[14];
    const float* dw_b   = (const float*)d_in[15];
    const float* pw_w   = (const float*)d_in[16];
    const float* pw_b   = (const float*)d_in[17];
    const float* bn_g   = (const float*)d_in[18];
    const float* bn_b   = (const float*)d_in[19];
    float* outF = (float*)d_out;

    char* ws = (char*)d_ws;
    float* XF = (float*)ws;
    short* Abuf = (short*)(ws + 50331648);
    short* Bbuf = (short*)(ws + 150994944);
    short* WT = (short*)(ws + 226492416);

    transpose_in<<<dim3(1024, 6, 2), dim3(32, 8), 0, stream>>>(x, XF);
    prep_w<<<7056, 256, 0, stream>>>(qkv_w, proj_w, fc1_w, fc2_w, pw_w, WT);

    for (int i = 0; i < 4; i++) {
        int shifted = i & 1;
        int shift = shifted ? 2 : 0;
        ln_k<true><<<16384, 256, 0, stream>>>(XF, n1g + i * 192, n1b + i * 192, Abuf, shift);
        gemm_k<0><<<4608, 256, 0, stream>>>(Abuf, WT + (long)i * 442368, qkv_b + i * 576,
                                            Bbuf, nullptr, nullptr, nullptr, nullptr,
                                            65536, 576, 192, 0);
        attn_k<<<1536, 256, 0, stream>>>(Bbuf, rpb + i * 2058, Abuf, shifted);
        gemm_k<3><<<1536, 256, 0, stream>>>(Abuf, WT + (long)i * 442368 + 110592, proj_b + i * 192,
                                            nullptr, XF, nullptr, nullptr, nullptr,
                                            65536, 192, 192, shift);
        mlp_k<<<512, 256, 0, stream>>>(XF, WT + (long)i * 442368 + 147456,
                                       WT + (long)i * 442368 + 294912,
                                       fc1_b + i * 768, fc2_b + i * 192,
                                       n2g + i * 192, n2b + i * 192, XF);
    }

    dw_k<<<8192, 192, 0, stream>>>(XF, dw_w, dw_b, Abuf);
    gemm_k<4><<<1536, 256, 0, stream>>>(Abuf, WT + 1769472, pw_b,
                                        nullptr, nullptr, outF, bn_g, bn_b,
                                        65536, 192, 192, 0);
}

// Round 7
// 766.532 us; speedup vs baseline: 1.3486x; 1.2423x over previous
//
#include <hip/hip_runtime.h>
#include <hip/hip_bf16.h>

// ---------------- constants ----------------
// C=192, H=W=T=32, WS=4, SS=2, NH=6, HD=32, N=64 tokens/window
// L = 32768 tokens/batch, B=2 -> M = 65536 rows everywhere.
#define DI __device__ __forceinline__

typedef short bf16x8 __attribute__((ext_vector_type(8)));
typedef float f32x4 __attribute__((ext_vector_type(4)));
typedef short s16x4 __attribute__((ext_vector_type(4)));

DI short f2bf(float f) {
    __hip_bfloat16 h = __float2bfloat16(f);
    return *reinterpret_cast<short*>(&h);
}

DI void gload_lds16(const short* gsrc, short* ldst) {
    __builtin_amdgcn_global_load_lds(
        (const __attribute__((address_space(1))) void*)gsrc,
        (__attribute__((address_space(3))) void*)ldst, 16, 0, 0);
}

// region label along one axis for the shift mask: [0,28)->0, [28,30)->1, [30,32)->2
DI int reg3(int p) { return p < 28 ? 0 : (p < 30 ? 1 : 2); }

// ---------------- input transpose: x (B,C,L) -> xf (B,L,C) f32 ----------------
__global__ __launch_bounds__(256) void transpose_in(const float* __restrict__ x,
                                                    float* __restrict__ xf) {
    __shared__ float tile[32][33];
    int b = blockIdx.z;
    int c0 = blockIdx.y * 32;
    int l0 = blockIdx.x * 32;
    int tx = threadIdx.x, ty = threadIdx.y;  // 32 x 8
#pragma unroll
    for (int i = 0; i < 32; i += 8)
        tile[ty + i][tx] = x[(long)(b * 192 + c0 + ty + i) * 32768 + l0 + tx];
    __syncthreads();
#pragma unroll
    for (int i = 0; i < 32; i += 8)
        xf[(long)(b * 32768 + l0 + ty + i) * 192 + c0 + tx] = tile[tx][ty + i];
}

// ---------------- weight prep ----------------
__global__ __launch_bounds__(256) void prep_w(const float* __restrict__ qkv_w,
                                              const float* __restrict__ proj_w,
                                              const float* __restrict__ fc1_w,
                                              const float* __restrict__ fc2_w,
                                              const float* __restrict__ pw_w,
                                              short* __restrict__ wt) {
    int i = blockIdx.x * 256 + threadIdx.x;
    float v;
    if (i < 1769472) {
        int b4 = i / 442368, r = i - b4 * 442368;
        if (r < 110592) { int n = r / 192, k = r - n * 192; v = qkv_w[b4 * 110592 + k * 576 + n]; }
        else if (r < 147456) { int r2 = r - 110592; int n = r2 / 192, k = r2 - n * 192; v = proj_w[b4 * 36864 + k * 192 + n]; }
        else if (r < 294912) { int r2 = r - 147456; int n = r2 / 192, k = r2 - n * 192; v = fc1_w[b4 * 147456 + k * 768 + n]; }
        else { int r2 = r - 294912; int n = r2 / 768, k = r2 - n * 768; v = fc2_w[b4 * 147456 + k * 192 + n]; }
        wt[i] = f2bf(v);
    } else {
        int r = i - 1769472;
        wt[i] = f2bf(pw_w[r]);
    }
}

// ---------------- LayerNorm (wave per token) fused roll+window-partition (LN1) ----------------
template <bool PART>
__global__ __launch_bounds__(256) void ln_k(const float* __restrict__ xf,
                                            const float* __restrict__ g,
                                            const float* __restrict__ bta,
                                            short* __restrict__ out, int shift) {
    int wv = threadIdx.x >> 6, lane = threadIdx.x & 63;
    int row = blockIdx.x * 4 + wv;
    long src;
    if (PART) {
        int b = row >> 15, r = row & 32767, widx = r >> 6, n = r & 63;
        int wh = widx >> 6, ww = (widx >> 3) & 7, wt = widx & 7;
        int ih = n >> 4, iw = (n >> 2) & 3, it = n & 3;
        int h = ((wh << 2) + ih + shift) & 31;
        int w = ((ww << 2) + iw + shift) & 31;
        int t = ((wt << 2) + it + shift) & 31;
        src = ((long)(b << 15) + (h << 10) + (w << 5) + t) * 192;
    } else {
        src = (long)row * 192;
    }
    float v[3], s = 0.f, sq = 0.f;
#pragma unroll
    for (int j = 0; j < 3; j++) {
        v[j] = xf[src + lane + 64 * j];
        s += v[j];
        sq += v[j] * v[j];
    }
#pragma unroll
    for (int o = 1; o < 64; o <<= 1) {
        s += __shfl_xor(s, o, 64);
        sq += __shfl_xor(sq, o, 64);
    }
    float mu = s * (1.f / 192.f);
    float var = sq * (1.f / 192.f) - mu * mu;
    float rstd = rsqrtf(var + 1e-5f);
    long dst = (long)row * 192;
#pragma unroll
    for (int j = 0; j < 3; j++) {
        int c = lane + 64 * j;
        out[dst + c] = f2bf((v[j] - mu) * rstd * g[c] + bta[c]);
    }
}

// ---------------- generic bf16 MFMA GEMM: out(M,N) = A(M,K) @ Bt(N,K)^T + bias ----------------
// MODE 0: out bf16   MODE 3: window-reverse+roll -> resid += v (proj)
// MODE 4: pointwise conv epilogue: BN + ReLU, write f32 channel-major output
template <int MODE>
__global__ __launch_bounds__(256) void gemm_k(
    const short* __restrict__ A, const short* __restrict__ Bt,
    const float* __restrict__ bias,
    short* __restrict__ outB, float* __restrict__ resid, float* __restrict__ outF,
    const float* __restrict__ bng, const float* __restrict__ bnb,
    int M, int N, int K, int shift) {
    __shared__ short As[128 * 64];
    __shared__ short Bs[64 * 64];
    const int tid = threadIdx.x;
    const int nwg = gridDim.x;
    const int wg = ((blockIdx.x & 7) * (nwg >> 3)) + (blockIdx.x >> 3);
    const int tiles_n = N >> 6;
    const int m0 = (wg / tiles_n) << 7;
    const int n0 = (wg % tiles_n) << 6;
    const int wv = tid >> 6, lane = tid & 63;
    const int lr = lane & 15, lg = lane >> 4;
    const int srow = lane >> 3;
    const int scb = ((lane & 7) ^ (lane >> 3)) << 3;

    f32x4 acc[2][4] = {};
    for (int kt = 0; kt < K; kt += 64) {
        __syncthreads();
#pragma unroll
        for (int i = 0; i < 4; i++) {
            int rbase = i * 32 + wv * 8;
            gload_lds16(A + (long)(m0 + rbase + srow) * K + kt + scb, As + rbase * 64);
        }
#pragma unroll
        for (int i = 0; i < 2; i++) {
            int rbase = i * 32 + wv * 8;
            gload_lds16(Bt + (long)(n0 + rbase + srow) * K + kt + scb, Bs + rbase * 64);
        }
        __syncthreads();
#pragma unroll
        for (int ks = 0; ks < 2; ks++) {
            bf16x8 af[2], bfv[4];
            int kb = (ks << 2) + lg;
#pragma unroll
            for (int mi = 0; mi < 2; mi++) {
                int r = (wv << 5) + (mi << 4) + lr;
                af[mi] = *(const bf16x8*)(As + r * 64 + ((kb ^ (r & 7)) << 3));
            }
#pragma unroll
            for (int ni = 0; ni < 4; ni++) {
                int r = (ni << 4) + lr;
                bfv[ni] = *(const bf16x8*)(Bs + r * 64 + ((kb ^ (r & 7)) << 3));
            }
#pragma unroll
            for (int mi = 0; mi < 2; mi++)
#pragma unroll
                for (int ni = 0; ni < 4; ni++)
                    acc[mi][ni] = __builtin_amdgcn_mfma_f32_16x16x32_bf16(
                        af[mi], bfv[ni], acc[mi][ni], 0, 0, 0);
        }
    }

#pragma unroll
    for (int mi = 0; mi < 2; mi++) {
        int rbase = m0 + (wv << 5) + (mi << 4) + (lg << 2);
#pragma unroll
        for (int ni = 0; ni < 4; ni++) {
            int col = n0 + (ni << 4) + lr;
            float bv = bias[col];
            if (MODE == 4) {
                float sc = 0.9999950000374997f * bng[col];
                float bb = bnb[col];
                f32x4 o;
#pragma unroll
                for (int e = 0; e < 4; e++) {
                    float v = (acc[mi][ni][e] + bv) * sc + bb;
                    o[e] = v > 0.f ? v : 0.f;
                }
                int b = rbase >> 15, l = rbase & 32767;
                *(f32x4*)(outF + ((long)(b * 192 + col) << 15) + l) = o;
            } else {
#pragma unroll
                for (int e = 0; e < 4; e++) {
                    int r = rbase + e;
                    float v = acc[mi][ni][e] + bv;
                    if (MODE == 0) {
                        outB[(long)r * N + col] = f2bf(v);
                    } else {  // MODE 3
                        int b = r >> 15, rr = r & 32767, widx = rr >> 6, n = rr & 63;
                        int wh = widx >> 6, ww = (widx >> 3) & 7, wt = widx & 7;
                        int ih = n >> 4, iw = (n >> 2) & 3, it = n & 3;
                        int h = ((wh << 2) + ih + shift) & 31;
                        int w = ((ww << 2) + iw + shift) & 31;
                        int t = ((wt << 2) + it + shift) & 31;
                        long tok = (long)(b << 15) + (h << 10) + (w << 5) + t;
                        resid[tok * 192 + col] += v;
                    }
                }
            }
        }
    }
}

// ---------------- fused LN2+MLP v5: resid += gelu(LN(x) @ W1 + b1) @ W2 + b2 ----------------
// Block = 256 rows, 8 waves (wave owns 32 rows), grid 256 = 1 block/CU.
// W chunks double-buffered in LDS via async global_load_lds (pre-swizzled source).
// GEMM1 swapped-operand -> hacc hidden-major -> packed b64 h-writes (wave-private).
// ONE barrier per chunk. LDS = 96KB W dbuf + 32KB h = 128KB.
__global__ __launch_bounds__(512, 2) void mlp_k(const float* __restrict__ XF,
                                                const short* __restrict__ W1g,  // fc1T (768,192)
                                                const short* __restrict__ W2g,  // fc2T (192,768)
                                                const float* __restrict__ b1,
                                                const float* __restrict__ b2,
                                                const float* __restrict__ n2g,
                                                const float* __restrict__ n2b,
                                                float* __restrict__ resid) {
    __shared__ short Wbuf[2][24576];  // per buf: W1 64x192 @0, W2 192x64 @12288
    __shared__ short Hs[16384];       // 8 waves x 32x64 (XOR-swizzled)
    const int tid = threadIdx.x;
    const int wv = tid >> 6, lane = tid & 63;
    const int lr = lane & 15, lg = lane >> 4;
    const int mt = ((blockIdx.x & 7) << 5) + (blockIdx.x >> 3);  // XCD swizzle, 256 blocks
    const int m0 = mt << 8;
    short* hw = Hs + (wv << 11);  // wave-private 32x64

    // ---- LN2 prologue: 32 rows/wave -> normalized bf16 fragments in registers ----
    bf16x8 areg[2][6];
#pragma unroll
    for (int mf = 0; mf < 2; mf++) {
        const float* rp = XF + (long)(m0 + (wv << 5) + (mf << 4) + lr) * 192;
        f32x4 xv[6][2];
        float s = 0.f, sq = 0.f;
#pragma unroll
        for (int kk = 0; kk < 6; kk++)
#pragma unroll
            for (int q = 0; q < 2; q++) {
                xv[kk][q] = *(const f32x4*)(rp + kk * 32 + (lg << 3) + q * 4);
#pragma unroll
                for (int e = 0; e < 4; e++) {
                    s += xv[kk][q][e];
                    sq += xv[kk][q][e] * xv[kk][q][e];
                }
            }
        s += __shfl_xor(s, 16, 64); s += __shfl_xor(s, 32, 64);
        sq += __shfl_xor(sq, 16, 64); sq += __shfl_xor(sq, 32, 64);
        float mu = s * (1.f / 192.f);
        float var = sq * (1.f / 192.f) - mu * mu;
        float rstd = rsqrtf(var + 1e-5f);
#pragma unroll
        for (int kk = 0; kk < 6; kk++) {
            int cb = kk * 32 + (lg << 3);
            f32x4 g0 = *(const f32x4*)(n2g + cb), g1 = *(const f32x4*)(n2g + cb + 4);
            f32x4 b0 = *(const f32x4*)(n2b + cb), b1v = *(const f32x4*)(n2b + cb + 4);
            bf16x8 t;
#pragma unroll
            for (int e = 0; e < 4; e++) {
                t[e] = f2bf((xv[kk][0][e] - mu) * rstd * g0[e] + b0[e]);
                t[e + 4] = f2bf((xv[kk][1][e] - mu) * rstd * g1[e] + b1v[e]);
            }
            areg[mf][kk] = t;
        }
    }

    // ---- async W chunk staging (pre-swizzled global source, linear LDS dest) ----
    auto stage = [&](int jc, int buf) {
#pragma unroll
        for (int q = 0; q < 3; q++) {  // W1 chunk: 64x192
            int base = (wv * 3 + q) * 512;
            int E = base + lane * 8;
            int row = E / 192;
            int cb = (E - row * 192) >> 3;
            gload_lds16(W1g + (long)(jc * 64 + row) * 192 + ((cb ^ (row & 7)) << 3),
                        &Wbuf[buf][base]);
        }
#pragma unroll
        for (int q = 0; q < 3; q++) {  // W2 chunk: 192x64
            int base = (wv * 3 + q) * 512;
            int E = base + lane * 8;
            int row = E >> 6;
            int cb = (E & 63) >> 3;
            gload_lds16(W2g + (long)row * 768 + jc * 64 + ((cb ^ (row & 7)) << 3),
                        &Wbuf[buf][12288 + base]);
        }
    };

    stage(0, 0);
    __syncthreads();  // drains vmcnt: chunk 0 staged

    f32x4 acc[2][12] = {};

    for (int j = 0; j < 12; j++) {
        if (j < 11) stage(j + 1, (j + 1) & 1);  // async prefetch, hidden under this chunk
        const short* W1s = Wbuf[j & 1];
        const short* W2s = Wbuf[j & 1] + 12288;

        // ---- GEMM1 (swapped): hacc[hidden][M] = W1frag x areg ----
        f32x4 hacc[4][2] = {};
#pragma unroll
        for (int kk = 0; kk < 6; kk++) {
            int cb = (kk << 2) + lg;
            bf16x8 wf[4];
#pragma unroll
            for (int hf = 0; hf < 4; hf++) {
                int r = (hf << 4) + lr;
                wf[hf] = *(const bf16x8*)(W1s + r * 192 + ((cb ^ (r & 7)) << 3));
            }
#pragma unroll
            for (int hf = 0; hf < 4; hf++)
#pragma unroll
                for (int mf = 0; mf < 2; mf++)
                    hacc[hf][mf] = __builtin_amdgcn_mfma_f32_16x16x32_bf16(
                        wf[hf], areg[mf][kk], hacc[hf][mf], 0, 0, 0);
        }

        // ---- GELU(+b1), packed b64 writes to wave-private h (row-major [M][hid]) ----
#pragma unroll
        for (int hf = 0; hf < 4; hf++) {
            f32x4 bv = *(const f32x4*)(b1 + j * 64 + (hf << 4) + (lg << 2));
#pragma unroll
            for (int mf = 0; mf < 2; mf++) {
                s16x4 hv;
#pragma unroll
                for (int e = 0; e < 4; e++) {
                    float v = hacc[hf][mf][e] + bv[e];
                    float inner = fmaf(-0.07135481627f, v * v, -1.595769122f);
                    float eterm = __expf(v * inner);  // exp(-2u)
                    float gl = v * __builtin_amdgcn_rcpf(1.f + eterm);
                    hv[e] = f2bf(gl);
                }
                int Mrow = (mf << 4) + lr;
                int blk = (hf << 1) | (lg >> 1);
                *(s16x4*)(hw + Mrow * 64 + ((blk ^ (Mrow & 7)) << 3) + ((lg & 1) << 2)) = hv;
            }
        }
        // wave-local h exchange: LDS queue drain only, no block barrier
        asm volatile("s_waitcnt lgkmcnt(0)" ::: "memory");

        // ---- GEMM2: acc += h @ W2 ----
#pragma unroll
        for (int kk = 0; kk < 2; kk++) {
            int cb = (kk << 2) + lg;
            bf16x8 ah[2], bw[12];
#pragma unroll
            for (int mf = 0; mf < 2; mf++) {
                int r = (mf << 4) + lr;
                ah[mf] = *(const bf16x8*)(hw + r * 64 + ((cb ^ (r & 7)) << 3));
            }
#pragma unroll
            for (int nj = 0; nj < 12; nj++) {
                int r = (nj << 4) + lr;
                bw[nj] = *(const bf16x8*)(W2s + r * 64 + ((cb ^ (r & 7)) << 3));
            }
#pragma unroll
            for (int mf = 0; mf < 2; mf++)
#pragma unroll
                for (int nj = 0; nj < 12; nj++)
                    acc[mf][nj] = __builtin_amdgcn_mfma_f32_16x16x32_bf16(
                        ah[mf], bw[nj], acc[mf][nj], 0, 0, 0);
        }
        // single barrier: waves done reading Wbuf[j&1]; vmcnt drained -> next buf ready
        __syncthreads();
    }

    // ---- epilogue: resid += acc + b2 ----
#pragma unroll
    for (int mf = 0; mf < 2; mf++) {
        int rbase = m0 + (wv << 5) + (mf << 4) + (lg << 2);
#pragma unroll
        for (int nj = 0; nj < 12; nj++) {
            int col = (nj << 4) + lr;
            float bv = b2[col];
#pragma unroll
            for (int e = 0; e < 4; e++) {
                long r = rbase + e;
                resid[r * 192 + col] += acc[mf][nj][e] + bv;
            }
        }
    }
}

// ---------------- windowed attention: one wave per (window, head) ----------------
__global__ __launch_bounds__(256) void attn_k(const short* __restrict__ qkv,
                                              const float* __restrict__ rpb,  // (343,6)
                                              short* __restrict__ o, int shifted) {
    __shared__ short lds[4 * 6144];
    const int wv = threadIdx.x >> 6, lane = threadIdx.x & 63;
    short* vT = lds + wv * 6144;
    short* P = lds + wv * 6144 + 2048;
    const int task = blockIdx.x * 4 + wv;
    const int win = task / 6, head = task - win * 6;
    const int lr = lane & 15, lg = lane >> 4;
    const long qbase = (long)win * 64 * 576 + head * 32;

    bf16x8 aq[4], bk[4];
#pragma unroll
    for (int bi = 0; bi < 4; bi++)
        aq[bi] = *(const bf16x8*)(qkv + qbase + (long)((bi << 4) + lr) * 576 + (lg << 3));
#pragma unroll
    for (int bj = 0; bj < 4; bj++)
        bk[bj] = *(const bf16x8*)(qkv + qbase + 192 + (long)((bj << 4) + lr) * 576 + (lg << 3));
    f32x4 s[4][4] = {};
#pragma unroll
    for (int bi = 0; bi < 4; bi++)
#pragma unroll
        for (int bj = 0; bj < 4; bj++)
            s[bi][bj] = __builtin_amdgcn_mfma_f32_16x16x32_bf16(aq[bi], bk[bj], s[bi][bj], 0, 0, 0);

#pragma unroll
    for (int j = 0; j < 4; j++) {
        bf16x8 vv = *(const bf16x8*)(qkv + qbase + 384 + (long)lane * 576 + (j << 3));
#pragma unroll
        for (int e = 0; e < 8; e++) {
            int d = (j << 3) + e;
            vT[d * 64 + (((lane >> 3) ^ (d & 7)) << 3) + (lane & 7)] = vv[e];
        }
    }

    const float SCALE = 0.17677669529663687f;
    int widx = win & 511;
    int wh = widx >> 6, ww = (widx >> 3) & 7, wt = widx & 7;
    int ihm[4], iwm[4], itm[4], lblm[4];
#pragma unroll
    for (int bj = 0; bj < 4; bj++) {
        int m = (bj << 4) + lr;
        ihm[bj] = m >> 4; iwm[bj] = (m >> 2) & 3; itm[bj] = m & 3;
        lblm[bj] = reg3((wh << 2) + ihm[bj]) * 9 + reg3((ww << 2) + iwm[bj]) * 3 + reg3((wt << 2) + itm[bj]);
    }
#pragma unroll
    for (int bi = 0; bi < 4; bi++) {
#pragma unroll
        for (int e = 0; e < 4; e++) {
            int n = (bi << 4) + (lg << 2) + e;
            int ihn = n >> 4, iwn = (n >> 2) & 3, itn = n & 3;
            int lbln = reg3((wh << 2) + ihn) * 9 + reg3((ww << 2) + iwn) * 3 + reg3((wt << 2) + itn);
#pragma unroll
            for (int bj = 0; bj < 4; bj++) {
                int idx = (ihn - ihm[bj] + 3) * 49 + (iwn - iwm[bj] + 3) * 7 + (itn - itm[bj] + 3);
                float bias = rpb[idx * 6 + head];
                float val = s[bi][bj][e] * SCALE + bias;
                if (shifted && lbln != lblm[bj]) val -= 100.f;
                s[bi][bj][e] = val;
            }
        }
    }

#pragma unroll
    for (int bi = 0; bi < 4; bi++) {
#pragma unroll
        for (int e = 0; e < 4; e++) {
            float mx = s[bi][0][e];
#pragma unroll
            for (int bj = 1; bj < 4; bj++) mx = fmaxf(mx, s[bi][bj][e]);
#pragma unroll
            for (int off = 1; off < 16; off <<= 1) mx = fmaxf(mx, __shfl_xor(mx, off, 64));
            float sm = 0.f;
#pragma unroll
            for (int bj = 0; bj < 4; bj++) {
                float p = __expf(s[bi][bj][e] - mx);
                s[bi][bj][e] = p;
                sm += p;
            }
#pragma unroll
            for (int off = 1; off < 16; off <<= 1) sm += __shfl_xor(sm, off, 64);
            float rinv = 1.f / sm;
            int n = (bi << 4) + (lg << 2) + e;
#pragma unroll
            for (int bj = 0; bj < 4; bj++) {
                int m = (bj << 4) + lr;
                P[n * 64 + (((m >> 3) ^ (n & 7)) << 3) + (m & 7)] = f2bf(s[bi][bj][e] * rinv);
            }
        }
    }

    f32x4 oacc[4][2] = {};
#pragma unroll
    for (int ks = 0; ks < 2; ks++) {
        bf16x8 ap[4], bv2[2];
        int kb = (ks << 2) + lg;
#pragma unroll
        for (int bi = 0; bi < 4; bi++) {
            int r = (bi << 4) + lr;
            ap[bi] = *(const bf16x8*)(P + r * 64 + ((kb ^ (r & 7)) << 3));
        }
#pragma unroll
        for (int nf = 0; nf < 2; nf++) {
            int d = (nf << 4) + lr;
            bv2[nf] = *(const bf16x8*)(vT + d * 64 + ((kb ^ (d & 7)) << 3));
        }
#pragma unroll
        for (int bi = 0; bi < 4; bi++)
#pragma unroll
            for (int nf = 0; nf < 2; nf++)
                oacc[bi][nf] = __builtin_amdgcn_mfma_f32_16x16x32_bf16(ap[bi], bv2[nf], oacc[bi][nf], 0, 0, 0);
    }
#pragma unroll
    for (int bi = 0; bi < 4; bi++)
#pragma unroll
        for (int nf = 0; nf < 2; nf++)
#pragma unroll
            for (int e = 0; e < 4; e++) {
                int n = (bi << 4) + (lg << 2) + e;
                int d = (nf << 4) + lr;
                o[((long)win * 64 + n) * 192 + head * 32 + d] = f2bf(oacc[bi][nf][e]);
            }
}

// ---------------- depthwise 3x3x3 conv, register-blocked along t ----------------
__global__ __launch_bounds__(192) void dw_k(const float* __restrict__ xf,
                                            const float* __restrict__ w,
                                            const float* __restrict__ db,
                                            short* __restrict__ out) {
    int c = threadIdx.x;
    int blk = blockIdx.x;
    int t0 = (blk & 3) << 3;
    int bhw = blk >> 2;
    int b = bhw >> 10, h = (bhw >> 5) & 31, wq = bhw & 31;

    float wr[27];
#pragma unroll
    for (int k = 0; k < 27; k++) wr[k] = w[c * 27 + k];
    float bias = db[c];
    float acc[8];
#pragma unroll
    for (int j = 0; j < 8; j++) acc[j] = bias;

#pragma unroll
    for (int a = 0; a < 3; a++) {
        int hh = h + a - 1;
        if (hh < 0 || hh > 31) continue;
#pragma unroll
        for (int bb = 0; bb < 3; bb++) {
            int ww = wq + bb - 1;
            if (ww < 0 || ww > 31) continue;
            const float* base = xf + ((long)(b << 15) + (hh << 10) + (ww << 5)) * 192 + c;
            float val[10];
#pragma unroll
            for (int tt = 0; tt < 10; tt++) {
                int t = t0 + tt - 1;
                val[tt] = (t >= 0 && t < 32) ? base[t * 192] : 0.f;
            }
#pragma unroll
            for (int d = 0; d < 3; d++) {
                float wv = wr[a * 9 + bb * 3 + d];
#pragma unroll
                for (int j = 0; j < 8; j++)
                    acc[j] = fmaf(val[j + d], wv, acc[j]);
            }
        }
    }
    long obase = ((long)(b << 15) + (h << 10) + (wq << 5) + t0) * 192 + c;
#pragma unroll
    for (int j = 0; j < 8; j++) out[obase + j * 192] = f2bf(acc[j]);
}

// ---------------- launch ----------------
extern "C" void kernel_launch(void* const* d_in, const int* in_sizes, int n_in,
                              void* d_out, int out_size, void* d_ws, size_t ws_size,
                              hipStream_t stream) {
    const float* x      = (const float*)d_in[0];
    const float* n1g    = (const float*)d_in[1];
    const float* n1b    = (const float*)d_in[2];
    const float* qkv_w  = (const float*)d_in[3];
    const float* qkv_b  = (const float*)d_in[4];
    const float* rpb    = (const float*)d_in[5];
    const float* proj_w = (const float*)d_in[6];
    const float* proj_b = (const float*)d_in[7];
    const float* n2g    = (const float*)d_in[8];
    const float* n2b    = (const float*)d_in[9];
    const float* fc1_w  = (const float*)d_in[10];
    const float* fc1_b  = (const float*)d_in[11];
    const float* fc2_w  = (const float*)d_in[12];
    const float* fc2_b  = (const float*)d_in[13];
    const float* dw_w   = (const float*)d_in[14];
    const float* dw_b   = (const float*)d_in[15];
    const float* pw_w   = (const float*)d_in[16];
    const float* pw_b   = (const float*)d_in[17];
    const float* bn_g   = (const float*)d_in[18];
    const float* bn_b   = (const float*)d_in[19];
    float* outF = (float*)d_out;

    char* ws = (char*)d_ws;
    float* XF = (float*)ws;
    short* Abuf = (short*)(ws + 50331648);
    short* Bbuf = (short*)(ws + 150994944);
    short* WT = (short*)(ws + 226492416);

    transpose_in<<<dim3(1024, 6, 2), dim3(32, 8), 0, stream>>>(x, XF);
    prep_w<<<7056, 256, 0, stream>>>(qkv_w, proj_w, fc1_w, fc2_w, pw_w, WT);

    for (int i = 0; i < 4; i++) {
        int shifted = i & 1;
        int shift = shifted ? 2 : 0;
        ln_k<true><<<16384, 256, 0, stream>>>(XF, n1g + i * 192, n1b + i * 192, Abuf, shift);
        gemm_k<0><<<4608, 256, 0, stream>>>(Abuf, WT + (long)i * 442368, qkv_b + i * 576,
                                            Bbuf, nullptr, nullptr, nullptr, nullptr,
                                            65536, 576, 192, 0);
        attn_k<<<1536, 256, 0, stream>>>(Bbuf, rpb + i * 2058, Abuf, shifted);
        gemm_k<3><<<1536, 256, 0, stream>>>(Abuf, WT + (long)i * 442368 + 110592, proj_b + i * 192,
                                            nullptr, XF, nullptr, nullptr, nullptr,
                                            65536, 192, 192, shift);
        mlp_k<<<256, 512, 0, stream>>>(XF, WT + (long)i * 442368 + 147456,
                                       WT + (long)i * 442368 + 294912,
                                       fc1_b + i * 768, fc2_b + i * 192,
                                       n2g + i * 192, n2b + i * 192, XF);
    }

    dw_k<<<8192, 192, 0, stream>>>(XF, dw_w, dw_b, Abuf);
    gemm_k<4><<<1536, 256, 0, stream>>>(Abuf, WT + 1769472, pw_b,
                                        nullptr, nullptr, outF, bn_g, bn_b,
                                        65536, 192, 192, 0);
}

// Round 8
// 708.079 us; speedup vs baseline: 1.4599x; 1.0826x over previous
//
#include <hip/hip_runtime.h>
#include <hip/hip_bf16.h>

// ---------------- constants ----------------
// C=192, H=W=T=32, WS=4, SS=2, NH=6, HD=32, N=64 tokens/window
// L = 32768 tokens/batch, B=2 -> M = 65536 rows everywhere.
#define DI __device__ __forceinline__

typedef short bf16x8 __attribute__((ext_vector_type(8)));
typedef float f32x4 __attribute__((ext_vector_type(4)));
typedef short s16x4 __attribute__((ext_vector_type(4)));

DI short f2bf(float f) {
    __hip_bfloat16 h = __float2bfloat16(f);
    return *reinterpret_cast<short*>(&h);
}

DI void gload_lds16(const short* gsrc, short* ldst) {
    __builtin_amdgcn_global_load_lds(
        (const __attribute__((address_space(1))) void*)gsrc,
        (__attribute__((address_space(3))) void*)ldst, 16, 0, 0);
}

// region label along one axis for the shift mask: [0,28)->0, [28,30)->1, [30,32)->2
DI int reg3(int p) { return p < 28 ? 0 : (p < 30 ? 1 : 2); }

// ---------------- input transpose: x (B,C,L) -> xf (B,L,C) f32 ----------------
__global__ __launch_bounds__(256) void transpose_in(const float* __restrict__ x,
                                                    float* __restrict__ xf) {
    __shared__ float tile[32][33];
    int b = blockIdx.z;
    int c0 = blockIdx.y * 32;
    int l0 = blockIdx.x * 32;
    int tx = threadIdx.x, ty = threadIdx.y;  // 32 x 8
#pragma unroll
    for (int i = 0; i < 32; i += 8)
        tile[ty + i][tx] = x[(long)(b * 192 + c0 + ty + i) * 32768 + l0 + tx];
    __syncthreads();
#pragma unroll
    for (int i = 0; i < 32; i += 8)
        xf[(long)(b * 32768 + l0 + ty + i) * 192 + c0 + tx] = tile[tx][ty + i];
}

// ---------------- weight prep ----------------
__global__ __launch_bounds__(256) void prep_w(const float* __restrict__ qkv_w,
                                              const float* __restrict__ proj_w,
                                              const float* __restrict__ fc1_w,
                                              const float* __restrict__ fc2_w,
                                              const float* __restrict__ pw_w,
                                              short* __restrict__ wt) {
    int i = blockIdx.x * 256 + threadIdx.x;
    float v;
    if (i < 1769472) {
        int b4 = i / 442368, r = i - b4 * 442368;
        if (r < 110592) { int n = r / 192, k = r - n * 192; v = qkv_w[b4 * 110592 + k * 576 + n]; }
        else if (r < 147456) { int r2 = r - 110592; int n = r2 / 192, k = r2 - n * 192; v = proj_w[b4 * 36864 + k * 192 + n]; }
        else if (r < 294912) { int r2 = r - 147456; int n = r2 / 192, k = r2 - n * 192; v = fc1_w[b4 * 147456 + k * 768 + n]; }
        else { int r2 = r - 294912; int n = r2 / 768, k = r2 - n * 768; v = fc2_w[b4 * 147456 + k * 192 + n]; }
        wt[i] = f2bf(v);
    } else {
        int r = i - 1769472;
        wt[i] = f2bf(pw_w[r]);
    }
}

// ---------------- fused LN1 + QKV: out = LN(gather(x)) @ Wqkv + b ----------------
// Block = 128 rows (window order), 4 waves x 32 rows. A (LN'd) lives in registers.
// W: 9 chunks of 64 cols, double-buffered LDS via async global_load_lds.
__global__ __launch_bounds__(256) void qkv_k(const float* __restrict__ XF,
                                             const short* __restrict__ Wg,  // qkvT (576,192)
                                             const float* __restrict__ bias,
                                             const float* __restrict__ n1g,
                                             const float* __restrict__ n1b,
                                             short* __restrict__ out, int shift) {
    __shared__ short Ws[2][12288];
    const int tid = threadIdx.x;
    const int wv = tid >> 6, lane = tid & 63;
    const int lr = lane & 15, lg = lane >> 4;
    const int mt = ((blockIdx.x & 7) << 6) + (blockIdx.x >> 3);  // XCD swizzle, 512 blocks
    const int m0 = mt << 7;

    // ---- LN1 prologue with roll+window-partition gather ----
    bf16x8 areg[2][6];
#pragma unroll
    for (int mf = 0; mf < 2; mf++) {
        int row = m0 + (wv << 5) + (mf << 4) + lr;
        int b = row >> 15, r = row & 32767, widx = r >> 6, n = r & 63;
        int wh = widx >> 6, ww = (widx >> 3) & 7, wt = widx & 7;
        int ih = n >> 4, iw = (n >> 2) & 3, it = n & 3;
        int h = ((wh << 2) + ih + shift) & 31;
        int w = ((ww << 2) + iw + shift) & 31;
        int t = ((wt << 2) + it + shift) & 31;
        const float* rp = XF + ((long)(b << 15) + (h << 10) + (w << 5) + t) * 192;
        f32x4 xv[6][2];
        float s = 0.f, sq = 0.f;
#pragma unroll
        for (int kk = 0; kk < 6; kk++)
#pragma unroll
            for (int q = 0; q < 2; q++) {
                xv[kk][q] = *(const f32x4*)(rp + kk * 32 + (lg << 3) + q * 4);
#pragma unroll
                for (int e = 0; e < 4; e++) {
                    s += xv[kk][q][e];
                    sq += xv[kk][q][e] * xv[kk][q][e];
                }
            }
        s += __shfl_xor(s, 16, 64); s += __shfl_xor(s, 32, 64);
        sq += __shfl_xor(sq, 16, 64); sq += __shfl_xor(sq, 32, 64);
        float mu = s * (1.f / 192.f);
        float var = sq * (1.f / 192.f) - mu * mu;
        float rstd = rsqrtf(var + 1e-5f);
#pragma unroll
        for (int kk = 0; kk < 6; kk++) {
            int cb = kk * 32 + (lg << 3);
            f32x4 g0 = *(const f32x4*)(n1g + cb), g1 = *(const f32x4*)(n1g + cb + 4);
            f32x4 b0 = *(const f32x4*)(n1b + cb), b1v = *(const f32x4*)(n1b + cb + 4);
            bf16x8 tt;
#pragma unroll
            for (int e = 0; e < 4; e++) {
                tt[e] = f2bf((xv[kk][0][e] - mu) * rstd * g0[e] + b0[e]);
                tt[e + 4] = f2bf((xv[kk][1][e] - mu) * rstd * g1[e] + b1v[e]);
            }
            areg[mf][kk] = tt;
        }
    }

    // ---- async W chunk staging (pre-swizzled source, linear dest) ----
    auto stage = [&](int jc, int buf) {
#pragma unroll
        for (int q = 0; q < 6; q++) {
            int base = (wv * 6 + q) * 512;
            int E = base + lane * 8;
            int row = E / 192;
            int cb = (E - row * 192) >> 3;
            gload_lds16(Wg + (long)(jc * 64 + row) * 192 + ((cb ^ (row & 7)) << 3),
                        &Ws[buf][base]);
        }
    };

    stage(0, 0);
    __syncthreads();

    for (int j = 0; j < 9; j++) {
        if (j < 8) stage(j + 1, (j + 1) & 1);
        const short* W = Ws[j & 1];
        f32x4 acc[2][4] = {};
#pragma unroll
        for (int kk = 0; kk < 6; kk++) {
            int cb = (kk << 2) + lg;
            bf16x8 wf[4];
#pragma unroll
            for (int nf = 0; nf < 4; nf++) {
                int r = (nf << 4) + lr;
                wf[nf] = *(const bf16x8*)(W + r * 192 + ((cb ^ (r & 7)) << 3));
            }
#pragma unroll
            for (int mf = 0; mf < 2; mf++)
#pragma unroll
                for (int nf = 0; nf < 4; nf++)
                    acc[mf][nf] = __builtin_amdgcn_mfma_f32_16x16x32_bf16(
                        areg[mf][kk], wf[nf], acc[mf][nf], 0, 0, 0);
        }
        // store chunk output
#pragma unroll
        for (int mf = 0; mf < 2; mf++) {
#pragma unroll
            for (int nf = 0; nf < 4; nf++) {
                int col = j * 64 + (nf << 4) + lr;
                float bv = bias[col];
#pragma unroll
                for (int e = 0; e < 4; e++) {
                    int row = m0 + (wv << 5) + (mf << 4) + (lg << 2) + e;
                    out[(long)row * 576 + col] = f2bf(acc[mf][nf][e] + bv);
                }
            }
        }
        __syncthreads();
    }
}

// ---------------- A-in-regs GEMM with full W in LDS (K=192, N=192) ----------------
// MODE 3: proj -> window-reverse+roll, resid += v
// MODE 4: pointwise conv -> BN + ReLU, f32 channel-major out
template <int MODE>
__global__ __launch_bounds__(256) void wk_k(const short* __restrict__ A,
                                            const short* __restrict__ Wg,  // (192,192)
                                            const float* __restrict__ bias,
                                            float* __restrict__ resid, float* __restrict__ outF,
                                            const float* __restrict__ bng,
                                            const float* __restrict__ bnb, int shift) {
    __shared__ short Ws[36864];
    const int tid = threadIdx.x;
    const int wv = tid >> 6, lane = tid & 63;
    const int lr = lane & 15, lg = lane >> 4;
    const int mt = ((blockIdx.x & 7) << 6) + (blockIdx.x >> 3);  // 512 blocks
    const int m0 = mt << 7;

    // A rows straight into registers
    bf16x8 areg[2][6];
#pragma unroll
    for (int mf = 0; mf < 2; mf++)
#pragma unroll
        for (int kk = 0; kk < 6; kk++)
            areg[mf][kk] = *(const bf16x8*)(A + (long)(m0 + (wv << 5) + (mf << 4) + lr) * 192 + kk * 32 + (lg << 3));

    // stage full W (async, pre-swizzled source)
#pragma unroll
    for (int q = 0; q < 18; q++) {
        int base = (wv * 18 + q) * 512;
        int E = base + lane * 8;
        int row = E / 192;
        int cb = (E - row * 192) >> 3;
        gload_lds16(Wg + (long)row * 192 + ((cb ^ (row & 7)) << 3), Ws + base);
    }
    __syncthreads();

    f32x4 acc[2][12] = {};
#pragma unroll
    for (int kk = 0; kk < 6; kk++) {
        int cb = (kk << 2) + lg;
#pragma unroll
        for (int njb = 0; njb < 3; njb++) {
            bf16x8 wf[4];
#pragma unroll
            for (int q = 0; q < 4; q++) {
                int r = ((njb * 4 + q) << 4) + lr;
                wf[q] = *(const bf16x8*)(Ws + r * 192 + ((cb ^ (r & 7)) << 3));
            }
#pragma unroll
            for (int mf = 0; mf < 2; mf++)
#pragma unroll
                for (int q = 0; q < 4; q++)
                    acc[mf][njb * 4 + q] = __builtin_amdgcn_mfma_f32_16x16x32_bf16(
                        areg[mf][kk], wf[q], acc[mf][njb * 4 + q], 0, 0, 0);
        }
    }

    // epilogue
#pragma unroll
    for (int mf = 0; mf < 2; mf++) {
        int rbase = m0 + (wv << 5) + (mf << 4) + (lg << 2);
#pragma unroll
        for (int nj = 0; nj < 12; nj++) {
            int col = (nj << 4) + lr;
            float bv = bias[col];
            if (MODE == 4) {
                float sc = 0.9999950000374997f * bng[col];
                float bb = bnb[col];
                f32x4 o;
#pragma unroll
                for (int e = 0; e < 4; e++) {
                    float v = (acc[mf][nj][e] + bv) * sc + bb;
                    o[e] = v > 0.f ? v : 0.f;
                }
                int b = rbase >> 15, l = rbase & 32767;
                *(f32x4*)(outF + ((long)(b * 192 + col) << 15) + l) = o;
            } else {  // MODE 3
#pragma unroll
                for (int e = 0; e < 4; e++) {
                    int r = rbase + e;
                    int b = r >> 15, rr = r & 32767, widx = rr >> 6, n = rr & 63;
                    int wh = widx >> 6, ww = (widx >> 3) & 7, wt = widx & 7;
                    int ih = n >> 4, iw = (n >> 2) & 3, it = n & 3;
                    int h = ((wh << 2) + ih + shift) & 31;
                    int w = ((ww << 2) + iw + shift) & 31;
                    int t = ((wt << 2) + it + shift) & 31;
                    long tok = (long)(b << 15) + (h << 10) + (w << 5) + t;
                    resid[tok * 192 + col] += acc[mf][nj][e] + bv;
                }
            }
        }
    }
}

// ---------------- fused LN2+MLP v5 (unchanged from r7) ----------------
__global__ __launch_bounds__(512, 2) void mlp_k(const float* __restrict__ XF,
                                                const short* __restrict__ W1g,  // fc1T (768,192)
                                                const short* __restrict__ W2g,  // fc2T (192,768)
                                                const float* __restrict__ b1,
                                                const float* __restrict__ b2,
                                                const float* __restrict__ n2g,
                                                const float* __restrict__ n2b,
                                                float* __restrict__ resid) {
    __shared__ short Wbuf[2][24576];  // per buf: W1 64x192 @0, W2 192x64 @12288
    __shared__ short Hs[16384];       // 8 waves x 32x64 (XOR-swizzled)
    const int tid = threadIdx.x;
    const int wv = tid >> 6, lane = tid & 63;
    const int lr = lane & 15, lg = lane >> 4;
    const int mt = ((blockIdx.x & 7) << 5) + (blockIdx.x >> 3);  // XCD swizzle, 256 blocks
    const int m0 = mt << 8;
    short* hw = Hs + (wv << 11);  // wave-private 32x64

    bf16x8 areg[2][6];
#pragma unroll
    for (int mf = 0; mf < 2; mf++) {
        const float* rp = XF + (long)(m0 + (wv << 5) + (mf << 4) + lr) * 192;
        f32x4 xv[6][2];
        float s = 0.f, sq = 0.f;
#pragma unroll
        for (int kk = 0; kk < 6; kk++)
#pragma unroll
            for (int q = 0; q < 2; q++) {
                xv[kk][q] = *(const f32x4*)(rp + kk * 32 + (lg << 3) + q * 4);
#pragma unroll
                for (int e = 0; e < 4; e++) {
                    s += xv[kk][q][e];
                    sq += xv[kk][q][e] * xv[kk][q][e];
                }
            }
        s += __shfl_xor(s, 16, 64); s += __shfl_xor(s, 32, 64);
        sq += __shfl_xor(sq, 16, 64); sq += __shfl_xor(sq, 32, 64);
        float mu = s * (1.f / 192.f);
        float var = sq * (1.f / 192.f) - mu * mu;
        float rstd = rsqrtf(var + 1e-5f);
#pragma unroll
        for (int kk = 0; kk < 6; kk++) {
            int cb = kk * 32 + (lg << 3);
            f32x4 g0 = *(const f32x4*)(n2g + cb), g1 = *(const f32x4*)(n2g + cb + 4);
            f32x4 b0 = *(const f32x4*)(n2b + cb), b1v = *(const f32x4*)(n2b + cb + 4);
            bf16x8 t;
#pragma unroll
            for (int e = 0; e < 4; e++) {
                t[e] = f2bf((xv[kk][0][e] - mu) * rstd * g0[e] + b0[e]);
                t[e + 4] = f2bf((xv[kk][1][e] - mu) * rstd * g1[e] + b1v[e]);
            }
            areg[mf][kk] = t;
        }
    }

    auto stage = [&](int jc, int buf) {
#pragma unroll
        for (int q = 0; q < 3; q++) {  // W1 chunk: 64x192
            int base = (wv * 3 + q) * 512;
            int E = base + lane * 8;
            int row = E / 192;
            int cb = (E - row * 192) >> 3;
            gload_lds16(W1g + (long)(jc * 64 + row) * 192 + ((cb ^ (row & 7)) << 3),
                        &Wbuf[buf][base]);
        }
#pragma unroll
        for (int q = 0; q < 3; q++) {  // W2 chunk: 192x64
            int base = (wv * 3 + q) * 512;
            int E = base + lane * 8;
            int row = E >> 6;
            int cb = (E & 63) >> 3;
            gload_lds16(W2g + (long)row * 768 + jc * 64 + ((cb ^ (row & 7)) << 3),
                        &Wbuf[buf][12288 + base]);
        }
    };

    stage(0, 0);
    __syncthreads();

    f32x4 acc[2][12] = {};

    for (int j = 0; j < 12; j++) {
        if (j < 11) stage(j + 1, (j + 1) & 1);
        const short* W1s = Wbuf[j & 1];
        const short* W2s = Wbuf[j & 1] + 12288;

        f32x4 hacc[4][2] = {};
#pragma unroll
        for (int kk = 0; kk < 6; kk++) {
            int cb = (kk << 2) + lg;
            bf16x8 wf[4];
#pragma unroll
            for (int hf = 0; hf < 4; hf++) {
                int r = (hf << 4) + lr;
                wf[hf] = *(const bf16x8*)(W1s + r * 192 + ((cb ^ (r & 7)) << 3));
            }
#pragma unroll
            for (int hf = 0; hf < 4; hf++)
#pragma unroll
                for (int mf = 0; mf < 2; mf++)
                    hacc[hf][mf] = __builtin_amdgcn_mfma_f32_16x16x32_bf16(
                        wf[hf], areg[mf][kk], hacc[hf][mf], 0, 0, 0);
        }

#pragma unroll
        for (int hf = 0; hf < 4; hf++) {
            f32x4 bv = *(const f32x4*)(b1 + j * 64 + (hf << 4) + (lg << 2));
#pragma unroll
            for (int mf = 0; mf < 2; mf++) {
                s16x4 hv;
#pragma unroll
                for (int e = 0; e < 4; e++) {
                    float v = hacc[hf][mf][e] + bv[e];
                    float inner = fmaf(-0.07135481627f, v * v, -1.595769122f);
                    float eterm = __expf(v * inner);  // exp(-2u)
                    float gl = v * __builtin_amdgcn_rcpf(1.f + eterm);
                    hv[e] = f2bf(gl);
                }
                int Mrow = (mf << 4) + lr;
                int blk = (hf << 1) | (lg >> 1);
                *(s16x4*)(hw + Mrow * 64 + ((blk ^ (Mrow & 7)) << 3) + ((lg & 1) << 2)) = hv;
            }
        }
        asm volatile("s_waitcnt lgkmcnt(0)" ::: "memory");

#pragma unroll
        for (int kk = 0; kk < 2; kk++) {
            int cb = (kk << 2) + lg;
            bf16x8 ah[2], bw[12];
#pragma unroll
            for (int mf = 0; mf < 2; mf++) {
                int r = (mf << 4) + lr;
                ah[mf] = *(const bf16x8*)(hw + r * 64 + ((cb ^ (r & 7)) << 3));
            }
#pragma unroll
            for (int nj = 0; nj < 12; nj++) {
                int r = (nj << 4) + lr;
                bw[nj] = *(const bf16x8*)(W2s + r * 64 + ((cb ^ (r & 7)) << 3));
            }
#pragma unroll
            for (int mf = 0; mf < 2; mf++)
#pragma unroll
                for (int nj = 0; nj < 12; nj++)
                    acc[mf][nj] = __builtin_amdgcn_mfma_f32_16x16x32_bf16(
                        ah[mf], bw[nj], acc[mf][nj], 0, 0, 0);
        }
        __syncthreads();
    }

#pragma unroll
    for (int mf = 0; mf < 2; mf++) {
        int rbase = m0 + (wv << 5) + (mf << 4) + (lg << 2);
#pragma unroll
        for (int nj = 0; nj < 12; nj++) {
            int col = (nj << 4) + lr;
            float bv = b2[col];
#pragma unroll
            for (int e = 0; e < 4; e++) {
                long r = rbase + e;
                resid[r * 192 + col] += acc[mf][nj][e] + bv;
            }
        }
    }
}

// ---------------- windowed attention: one wave per (window, head) ----------------
__global__ __launch_bounds__(256) void attn_k(const short* __restrict__ qkv,
                                              const float* __restrict__ rpb,  // (343,6)
                                              short* __restrict__ o, int shifted) {
    __shared__ short lds[4 * 6144];
    const int wv = threadIdx.x >> 6, lane = threadIdx.x & 63;
    short* vT = lds + wv * 6144;
    short* P = lds + wv * 6144 + 2048;
    const int task = blockIdx.x * 4 + wv;
    const int win = task / 6, head = task - win * 6;
    const int lr = lane & 15, lg = lane >> 4;
    const long qbase = (long)win * 64 * 576 + head * 32;

    bf16x8 aq[4], bk[4];
#pragma unroll
    for (int bi = 0; bi < 4; bi++)
        aq[bi] = *(const bf16x8*)(qkv + qbase + (long)((bi << 4) + lr) * 576 + (lg << 3));
#pragma unroll
    for (int bj = 0; bj < 4; bj++)
        bk[bj] = *(const bf16x8*)(qkv + qbase + 192 + (long)((bj << 4) + lr) * 576 + (lg << 3));
    f32x4 s[4][4] = {};
#pragma unroll
    for (int bi = 0; bi < 4; bi++)
#pragma unroll
        for (int bj = 0; bj < 4; bj++)
            s[bi][bj] = __builtin_amdgcn_mfma_f32_16x16x32_bf16(aq[bi], bk[bj], s[bi][bj], 0, 0, 0);

#pragma unroll
    for (int j = 0; j < 4; j++) {
        bf16x8 vv = *(const bf16x8*)(qkv + qbase + 384 + (long)lane * 576 + (j << 3));
#pragma unroll
        for (int e = 0; e < 8; e++) {
            int d = (j << 3) + e;
            vT[d * 64 + (((lane >> 3) ^ (d & 7)) << 3) + (lane & 7)] = vv[e];
        }
    }

    const float SCALE = 0.17677669529663687f;
    int widx = win & 511;
    int wh = widx >> 6, ww = (widx >> 3) & 7, wt = widx & 7;
    int ihm[4], iwm[4], itm[4], lblm[4];
#pragma unroll
    for (int bj = 0; bj < 4; bj++) {
        int m = (bj << 4) + lr;
        ihm[bj] = m >> 4; iwm[bj] = (m >> 2) & 3; itm[bj] = m & 3;
        lblm[bj] = reg3((wh << 2) + ihm[bj]) * 9 + reg3((ww << 2) + iwm[bj]) * 3 + reg3((wt << 2) + itm[bj]);
    }
#pragma unroll
    for (int bi = 0; bi < 4; bi++) {
#pragma unroll
        for (int e = 0; e < 4; e++) {
            int n = (bi << 4) + (lg << 2) + e;
            int ihn = n >> 4, iwn = (n >> 2) & 3, itn = n & 3;
            int lbln = reg3((wh << 2) + ihn) * 9 + reg3((ww << 2) + iwn) * 3 + reg3((wt << 2) + itn);
#pragma unroll
            for (int bj = 0; bj < 4; bj++) {
                int idx = (ihn - ihm[bj] + 3) * 49 + (iwn - iwm[bj] + 3) * 7 + (itn - itm[bj] + 3);
                float bias = rpb[idx * 6 + head];
                float val = s[bi][bj][e] * SCALE + bias;
                if (shifted && lbln != lblm[bj]) val -= 100.f;
                s[bi][bj][e] = val;
            }
        }
    }

#pragma unroll
    for (int bi = 0; bi < 4; bi++) {
#pragma unroll
        for (int e = 0; e < 4; e++) {
            float mx = s[bi][0][e];
#pragma unroll
            for (int bj = 1; bj < 4; bj++) mx = fmaxf(mx, s[bi][bj][e]);
#pragma unroll
            for (int off = 1; off < 16; off <<= 1) mx = fmaxf(mx, __shfl_xor(mx, off, 64));
            float sm = 0.f;
#pragma unroll
            for (int bj = 0; bj < 4; bj++) {
                float p = __expf(s[bi][bj][e] - mx);
                s[bi][bj][e] = p;
                sm += p;
            }
#pragma unroll
            for (int off = 1; off < 16; off <<= 1) sm += __shfl_xor(sm, off, 64);
            float rinv = 1.f / sm;
            int n = (bi << 4) + (lg << 2) + e;
#pragma unroll
            for (int bj = 0; bj < 4; bj++) {
                int m = (bj << 4) + lr;
                P[n * 64 + (((m >> 3) ^ (n & 7)) << 3) + (m & 7)] = f2bf(s[bi][bj][e] * rinv);
            }
        }
    }

    f32x4 oacc[4][2] = {};
#pragma unroll
    for (int ks = 0; ks < 2; ks++) {
        bf16x8 ap[4], bv2[2];
        int kb = (ks << 2) + lg;
#pragma unroll
        for (int bi = 0; bi < 4; bi++) {
            int r = (bi << 4) + lr;
            ap[bi] = *(const bf16x8*)(P + r * 64 + ((kb ^ (r & 7)) << 3));
        }
#pragma unroll
        for (int nf = 0; nf < 2; nf++) {
            int d = (nf << 4) + lr;
            bv2[nf] = *(const bf16x8*)(vT + d * 64 + ((kb ^ (d & 7)) << 3));
        }
#pragma unroll
        for (int bi = 0; bi < 4; bi++)
#pragma unroll
            for (int nf = 0; nf < 2; nf++)
                oacc[bi][nf] = __builtin_amdgcn_mfma_f32_16x16x32_bf16(ap[bi], bv2[nf], oacc[bi][nf], 0, 0, 0);
    }
#pragma unroll
    for (int bi = 0; bi < 4; bi++)
#pragma unroll
        for (int nf = 0; nf < 2; nf++)
#pragma unroll
            for (int e = 0; e < 4; e++) {
                int n = (bi << 4) + (lg << 2) + e;
                int d = (nf << 4) + lr;
                o[((long)win * 64 + n) * 192 + head * 32 + d] = f2bf(oacc[bi][nf][e]);
            }
}

// ---------------- depthwise 3x3x3 conv, register-blocked along t ----------------
__global__ __launch_bounds__(192) void dw_k(const float* __restrict__ xf,
                                            const float* __restrict__ w,
                                            const float* __restrict__ db,
                                            short* __restrict__ out) {
    int c = threadIdx.x;
    int blk = blockIdx.x;
    int t0 = (blk & 3) << 3;
    int bhw = blk >> 2;
    int b = bhw >> 10, h = (bhw >> 5) & 31, wq = bhw & 31;

    float wr[27];
#pragma unroll
    for (int k = 0; k < 27; k++) wr[k] = w[c * 27 + k];
    float bias = db[c];
    float acc[8];
#pragma unroll
    for (int j = 0; j < 8; j++) acc[j] = bias;

#pragma unroll
    for (int a = 0; a < 3; a++) {
        int hh = h + a - 1;
        if (hh < 0 || hh > 31) continue;
#pragma unroll
        for (int bb = 0; bb < 3; bb++) {
            int ww = wq + bb - 1;
            if (ww < 0 || ww > 31) continue;
            const float* base = xf + ((long)(b << 15) + (hh << 10) + (ww << 5)) * 192 + c;
            float val[10];
#pragma unroll
            for (int tt = 0; tt < 10; tt++) {
                int t = t0 + tt - 1;
                val[tt] = (t >= 0 && t < 32) ? base[t * 192] : 0.f;
            }
#pragma unroll
            for (int d = 0; d < 3; d++) {
                float wv = wr[a * 9 + bb * 3 + d];
#pragma unroll
                for (int j = 0; j < 8; j++)
                    acc[j] = fmaf(val[j + d], wv, acc[j]);
            }
        }
    }
    long obase = ((long)(b << 15) + (h << 10) + (wq << 5) + t0) * 192 + c;
#pragma unroll
    for (int j = 0; j < 8; j++) out[obase + j * 192] = f2bf(acc[j]);
}

// ---------------- launch ----------------
extern "C" void kernel_launch(void* const* d_in, const int* in_sizes, int n_in,
                              void* d_out, int out_size, void* d_ws, size_t ws_size,
                              hipStream_t stream) {
    const float* x      = (const float*)d_in[0];
    const float* n1g    = (const float*)d_in[1];
    const float* n1b    = (const float*)d_in[2];
    const float* qkv_w  = (const float*)d_in[3];
    const float* qkv_b  = (const float*)d_in[4];
    const float* rpb    = (const float*)d_in[5];
    const float* proj_w = (const float*)d_in[6];
    const float* proj_b = (const float*)d_in[7];
    const float* n2g    = (const float*)d_in[8];
    const float* n2b    = (const float*)d_in[9];
    const float* fc1_w  = (const float*)d_in[10];
    const float* fc1_b  = (const float*)d_in[11];
    const float* fc2_w  = (const float*)d_in[12];
    const float* fc2_b  = (const float*)d_in[13];
    const float* dw_w   = (const float*)d_in[14];
    const float* dw_b   = (const float*)d_in[15];
    const float* pw_w   = (const float*)d_in[16];
    const float* pw_b   = (const float*)d_in[17];
    const float* bn_g   = (const float*)d_in[18];
    const float* bn_b   = (const float*)d_in[19];
    float* outF = (float*)d_out;

    char* ws = (char*)d_ws;
    float* XF = (float*)ws;
    short* Abuf = (short*)(ws + 50331648);
    short* Bbuf = (short*)(ws + 150994944);
    short* WT = (short*)(ws + 226492416);

    transpose_in<<<dim3(1024, 6, 2), dim3(32, 8), 0, stream>>>(x, XF);
    prep_w<<<7056, 256, 0, stream>>>(qkv_w, proj_w, fc1_w, fc2_w, pw_w, WT);

    for (int i = 0; i < 4; i++) {
        int shifted = i & 1;
        int shift = shifted ? 2 : 0;
        qkv_k<<<512, 256, 0, stream>>>(XF, WT + (long)i * 442368, qkv_b + i * 576,
                                       n1g + i * 192, n1b + i * 192, Bbuf, shift);
        attn_k<<<1536, 256, 0, stream>>>(Bbuf, rpb + i * 2058, Abuf, shifted);
        wk_k<3><<<512, 256, 0, stream>>>(Abuf, WT + (long)i * 442368 + 110592, proj_b + i * 192,
                                         XF, nullptr, nullptr, nullptr, shift);
        mlp_k<<<256, 512, 0, stream>>>(XF, WT + (long)i * 442368 + 147456,
                                       WT + (long)i * 442368 + 294912,
                                       fc1_b + i * 768, fc2_b + i * 192,
                                       n2g + i * 192, n2b + i * 192, XF);
    }

    dw_k<<<8192, 192, 0, stream>>>(XF, dw_w, dw_b, Abuf);
    wk_k<4><<<512, 256, 0, stream>>>(Abuf, WT + 1769472, pw_b,
                                     nullptr, outF, bn_g, bn_b, 0);
}